// Round 1
// baseline (359.364 us; speedup 1.0000x reference)
//
#include <hip/hip_runtime.h>
#include <hip/hip_bf16.h>
#include <math.h>

typedef __bf16 bf16_t;
typedef bf16_t bf16x4 __attribute__((ext_vector_type(4)));
typedef bf16_t bf16x8 __attribute__((ext_vector_type(8)));
typedef float f32x4 __attribute__((ext_vector_type(4)));

#define Bsz 16
#define LCc 512
#define LQq 64
#define Hd 256
#define Dd 1024
#define DFFd 512
#define DP1 1025
#define KP 1056      // padded K for s1/e1/T/Wbt rows (33*32)
#define NP 1152      // padded row count for Wbt (9*128)
#define NROW 8192    // B*LC
#define YC 1536      // LC*3

// ---- workspace layout (bytes). T aliases the early-dead region. ----
#define OFF_T    0L
#define OFF_QW2  0L
#define OFF_MROW 4096L
#define OFF_Q2C  (OFF_MROW + 32768L)
#define OFF_C2Q  (OFF_Q2C + 16384L)
#define OFF_XB   (OFF_C2Q + 8388608L)
#define OFF_HBUF (OFF_XB + 16777216L)
#define OFF_W1ST (OFF_HBUF + 8388608L)
#define OFF_W2ST (OFF_W1ST + 1048576L)
#define OFF_W1ET (OFF_W2ST + 1048576L)
#define OFF_W2ET (OFF_W1ET + 1048576L)
// T size = 16*1536*1056*2 = 51904512 bytes
#define OFF_S1   51904512L
#define OFF_E1   (OFF_S1 + 17301504L)
#define OFF_WBT  (OFF_E1 + 17301504L)

static __device__ __forceinline__ void gload_lds16(const void* g, void* l) {
    __builtin_amdgcn_global_load_lds(
        (const __attribute__((address_space(1))) void*)g,
        (__attribute__((address_space(3))) void*)l, 16, 0, 0);
}

// ---------- qw2[b,j] = dot(ques[b,j,:], w2) ----------
__global__ __launch_bounds__(256) void k_qw2(const float* __restrict__ ques,
                                             const float* __restrict__ wsim,
                                             float* __restrict__ qw2) {
    int row = blockIdx.x * 4 + (threadIdx.x >> 6);   // b*64+j, 1024 rows
    int lane = threadIdx.x & 63;
    float4 q = *(const float4*)&ques[(long)row * Hd + lane * 4];
    float4 w = *(const float4*)&wsim[Hd + lane * 4];
    float p = q.x * w.x + q.y * w.y + q.z * w.z + q.w * w.w;
#pragma unroll
    for (int o = 32; o >= 1; o >>= 1) p += __shfl_xor(p, o, 64);
    if (lane == 0) qw2[row] = p;
}

// ---------- weight transpose f32 [K][N] -> bf16 [N][K] ----------
__global__ __launch_bounds__(256) void k_wtrans(const float* __restrict__ in,
                                                bf16_t* __restrict__ out,
                                                int K, int N) {
    __shared__ float tile[32][33];
    int k0 = blockIdx.x * 32, n0 = blockIdx.y * 32;
    int r = threadIdx.x >> 5, c = threadIdx.x & 31;
#pragma unroll
    for (int rr = 0; rr < 32; rr += 8)
        tile[r + rr][c] = in[(long)(k0 + r + rr) * N + n0 + c];
    __syncthreads();
#pragma unroll
    for (int rr = 0; rr < 32; rr += 8)
        out[(long)(n0 + r + rr) * K + k0 + c] = (bf16_t)tile[c][r + rr];
}

// ---------- Wbt[c][i][j] = Wb[i,c,j], bf16, zero-padded to [3][1152][1056] ----------
__global__ __launch_bounds__(256) void k_wb(const float* __restrict__ Wb,
                                            bf16_t* __restrict__ Wbt) {
    int rowz = blockIdx.x;          // c*1152 + i
    int c = rowz / NP, i = rowz % NP;
    int tid = threadIdx.x;
    bf16_t* orow = Wbt + (long)rowz * KP;
#pragma unroll
    for (int p = 0; p < 2; p++) {
        int j4 = tid + p * 256;
        if (j4 < 264) {
            int j = j4 * 4;
            float x = 0.f, y = 0.f, z = 0.f, w = 0.f;
            if (i < DP1) {
                const float* src = Wb + ((long)i * 3 + c) * DP1 + j;
                if (j + 0 < DP1) x = src[0];
                if (j + 1 < DP1) y = src[1];
                if (j + 2 < DP1) z = src[2];
                if (j + 3 < DP1) w = src[3];
            }
            bf16x4 bv = {(bf16_t)x, (bf16_t)y, (bf16_t)z, (bf16_t)w};
            *(bf16x4*)&orow[j] = bv;
        }
    }
}

// ---------- init ones/zero pad cols [1024..1055] of s1,e1 ----------
__global__ __launch_bounds__(256) void k_initse(bf16_t* __restrict__ s1,
                                                bf16_t* __restrict__ e1) {
    int idx = blockIdx.x * 256 + threadIdx.x;   // 8192*32
    long r = idx >> 5; int cc = idx & 31;
    bf16_t v = (bf16_t)(cc == 0 ? 1.0f : 0.0f);
    s1[r * KP + 1024 + cc] = v;
    e1[r * KP + 1024 + cc] = v;
}

// ---------- attention: sim -> softmax_j -> c2q, rowmax -> mrow ----------
__global__ __launch_bounds__(256) void k_attn(const float* __restrict__ ctx,
                                              const float* __restrict__ ques,
                                              const float* __restrict__ wsim,
                                              const float* __restrict__ qw2,
                                              float* __restrict__ c2q,
                                              float* __restrict__ mrow) {
    __shared__ bf16x4 qlds[LQq * 64];   // [j][64 chunks of 4 bf16], slot XOR (j&15)
    __shared__ float cw3s[4][Hd];
    __shared__ float awave[4][LQq];
    int b = blockIdx.x >> 5;
    int itile = blockIdx.x & 31;
    int tid = threadIdx.x, wid = tid >> 6, lane = tid & 63;
    // stage ques[b] as bf16, swizzled
#pragma unroll
    for (int p = 0; p < 16; p++) {
        int s = tid + p * 256;
        int j = s >> 6, h4s = s & 63;
        int h4 = h4s ^ (j & 15);
        float4 v = *(const float4*)&ques[((long)b * LQq + j) * Hd + h4 * 4];
        bf16x4 bv = {(bf16_t)v.x, (bf16_t)v.y, (bf16_t)v.z, (bf16_t)v.w};
        qlds[s] = bv;
    }
    float qw2r = qw2[b * LQq + lane];
    float4 w1v = *(const float4*)&wsim[lane * 4];
    float4 w3v = *(const float4*)&wsim[2 * Hd + lane * 4];
    __syncthreads();
    for (int rr = 0; rr < 4; rr++) {
        int i = itile * 16 + wid * 4 + rr;
        float4 cv = *(const float4*)&ctx[((long)b * LCc + i) * Hd + lane * 4];
        float cw1p = cv.x * w1v.x + cv.y * w1v.y + cv.z * w1v.z + cv.w * w1v.w;
        float4 c3;
        c3.x = cv.x * w3v.x; c3.y = cv.y * w3v.y;
        c3.z = cv.z * w3v.z; c3.w = cv.w * w3v.w;
        *(float4*)&cw3s[wid][lane * 4] = c3;
#pragma unroll
        for (int o = 32; o >= 1; o >>= 1) cw1p += __shfl_xor(cw1p, o, 64);
        __syncthreads();
        float s = cw1p + qw2r;   // lane = j
#pragma unroll 8
        for (int h4 = 0; h4 < 64; h4++) {
            float4 c3v = *(const float4*)&cw3s[wid][h4 * 4];
            bf16x4 qb = qlds[lane * 64 + (h4 ^ (lane & 15))];
            s += c3v.x * (float)qb[0] + c3v.y * (float)qb[1]
               + c3v.z * (float)qb[2] + c3v.w * (float)qb[3];
        }
        float mx = s;
#pragma unroll
        for (int o = 32; o >= 1; o >>= 1) mx = fmaxf(mx, __shfl_xor(mx, o, 64));
        if (lane == 0) mrow[b * LCc + i] = mx;
        float pe = __expf(s - mx);
        float den = pe;
#pragma unroll
        for (int o = 32; o >= 1; o >>= 1) den += __shfl_xor(den, o, 64);
        awave[wid][lane] = pe / den;
        __syncthreads();
        float4 accv = {0.f, 0.f, 0.f, 0.f};
#pragma unroll 8
        for (int j = 0; j < 64; j++) {
            float aj = awave[wid][j];
            bf16x4 qb = qlds[j * 64 + (lane ^ (j & 15))];
            accv.x = fmaf(aj, (float)qb[0], accv.x);
            accv.y = fmaf(aj, (float)qb[1], accv.y);
            accv.z = fmaf(aj, (float)qb[2], accv.z);
            accv.w = fmaf(aj, (float)qb[3], accv.w);
        }
        *(float4*)&c2q[((long)b * LCc + i) * Hd + lane * 4] = accv;
        __syncthreads();
    }
}

// ---------- q2c[b,h] = sum_i softmax_i(mrow)[i] * ctx[b,i,h] ----------
__global__ __launch_bounds__(256) void k_q2c(const float* __restrict__ ctx,
                                             const float* __restrict__ mrow,
                                             float* __restrict__ q2c) {
    __shared__ float wbuf[LCc];
    __shared__ float red[8];
    int b = blockIdx.x, tid = threadIdx.x;
    float v0 = mrow[b * LCc + tid], v1 = mrow[b * LCc + 256 + tid];
    float m = fmaxf(v0, v1);
#pragma unroll
    for (int o = 32; o >= 1; o >>= 1) m = fmaxf(m, __shfl_xor(m, o, 64));
    if ((tid & 63) == 0) red[tid >> 6] = m;
    __syncthreads();
    float M = fmaxf(fmaxf(red[0], red[1]), fmaxf(red[2], red[3]));
    float e0 = __expf(v0 - M), e1v = __expf(v1 - M);
    float sm = e0 + e1v;
#pragma unroll
    for (int o = 32; o >= 1; o >>= 1) sm += __shfl_xor(sm, o, 64);
    if ((tid & 63) == 0) red[4 + (tid >> 6)] = sm;
    __syncthreads();
    float S = red[4] + red[5] + red[6] + red[7];
    wbuf[tid] = e0 / S;
    wbuf[tid + 256] = e1v / S;
    __syncthreads();
    float acc = 0.f;
#pragma unroll 8
    for (int i = 0; i < LCc; i++)
        acc = fmaf(wbuf[i], ctx[((long)b * LCc + i) * Hd + tid], acc);
    q2c[b * Hd + tid] = acc;
}

// ---------- x = [ctx, c2q, ctx*c2q, ctx*q2c] -> bf16 [8192][1024] ----------
__global__ __launch_bounds__(256) void k_buildx(const float* __restrict__ ctx,
                                                const float* __restrict__ c2q,
                                                const float* __restrict__ q2c,
                                                bf16_t* __restrict__ xb) {
    long r = blockIdx.x;
    int b = (int)(r >> 9);
    int tid = threadIdx.x;
    int sec = tid >> 6, h4 = tid & 63;
    float4 cv = *(const float4*)&ctx[r * Hd + h4 * 4];
    float4 v;
    if (sec == 0) {
        v = cv;
    } else if (sec == 1) {
        v = *(const float4*)&c2q[r * Hd + h4 * 4];
    } else if (sec == 2) {
        float4 q = *(const float4*)&c2q[r * Hd + h4 * 4];
        v.x = cv.x * q.x; v.y = cv.y * q.y; v.z = cv.z * q.z; v.w = cv.w * q.w;
    } else {
        float4 q = *(const float4*)&q2c[b * Hd + h4 * 4];
        v.x = cv.x * q.x; v.y = cv.y * q.y; v.z = cv.z * q.z; v.w = cv.w * q.w;
    }
    bf16x4 bv = {(bf16_t)v.x, (bf16_t)v.y, (bf16_t)v.z, (bf16_t)v.w};
    *(bf16x4*)&xb[r * Dd + sec * Hd + h4 * 4] = bv;
}

// ---------- bf16 NT GEMM: C[M,N] = A[M,Kp] * Bt[N,Kp]^T, 128x128x32, 4 waves ----------
// MODE 0: +bias, relu, store bf16 ldc=512 (hbuf)
// MODE 1: +bias, store bf16 ldc=1056 (s1/e1)
// MODE 2: store bf16 T[(r*3+z)*1056+col], guard col<1056
// MODE 3: store f32 out[z*512*1536 + r*1536 + col]
template <int MODE>
__global__ __launch_bounds__(256, 2) void gemm_nt(
    const bf16_t* __restrict__ A, const bf16_t* __restrict__ B,
    const float* __restrict__ bias, void* __restrict__ C,
    int K, int lda, int ldb, long sAz, long sBz) {
    __shared__ bf16_t As[128 * 32];
    __shared__ bf16_t Bs[128 * 32];
    int tid = threadIdx.x;
    int wid = tid >> 6, lane = tid & 63;
    const bf16_t* Ab = A + (long)blockIdx.z * sAz + (long)blockIdx.x * 128 * lda;
    const bf16_t* Bb = B + (long)blockIdx.z * sBz + (long)blockIdx.y * 128 * ldb;
    int wr = (wid >> 1) * 64, wc = (wid & 1) * 64;
    int fr = lane & 15, kg = lane >> 4;
    f32x4 acc[4][4] = {};
    for (int k0 = 0; k0 < K; k0 += 32) {
        __syncthreads();
#pragma unroll
        for (int p = 0; p < 2; p++) {
            int q = tid + p * 256;
            int row = q >> 2, cg = q & 3;
            gload_lds16(Ab + (long)row * lda + k0 + cg * 8, &As[q * 8]);
            gload_lds16(Bb + (long)row * ldb + k0 + cg * 8, &Bs[q * 8]);
        }
        __syncthreads();
        bf16x8 af[4], bq[4];
#pragma unroll
        for (int m = 0; m < 4; m++)
            af[m] = *(const bf16x8*)&As[(wr + m * 16 + fr) * 32 + kg * 8];
#pragma unroll
        for (int n = 0; n < 4; n++)
            bq[n] = *(const bf16x8*)&Bs[(wc + n * 16 + fr) * 32 + kg * 8];
#pragma unroll
        for (int m = 0; m < 4; m++)
#pragma unroll
            for (int n = 0; n < 4; n++)
                acc[m][n] = __builtin_amdgcn_mfma_f32_16x16x32_bf16(
                    af[m], bq[n], acc[m][n], 0, 0, 0);
    }
    int g4 = (lane >> 4) * 4;
#pragma unroll
    for (int m = 0; m < 4; m++) {
#pragma unroll
        for (int g = 0; g < 4; g++) {
            long r = (long)blockIdx.x * 128 + wr + m * 16 + g4 + g;
#pragma unroll
            for (int n = 0; n < 4; n++) {
                int col = blockIdx.y * 128 + wc + n * 16 + fr;
                float v = acc[m][n][g];
                if (MODE == 0) {
                    v += bias[col];
                    v = fmaxf(v, 0.f);
                    ((bf16_t*)C)[r * DFFd + col] = (bf16_t)v;
                } else if (MODE == 1) {
                    v += bias[col];
                    ((bf16_t*)C)[r * KP + col] = (bf16_t)v;
                } else if (MODE == 2) {
                    if (col < KP)
                        ((bf16_t*)C)[(r * 3 + blockIdx.z) * KP + col] = (bf16_t)v;
                } else {
                    ((float*)C)[(long)blockIdx.z * (LCc * YC) + r * YC + col] = v;
                }
            }
        }
    }
}

extern "C" void kernel_launch(void* const* d_in, const int* in_sizes, int n_in,
                              void* d_out, int out_size, void* d_ws, size_t ws_size,
                              hipStream_t stream) {
    const float* ctx  = (const float*)d_in[0];
    const float* ques = (const float*)d_in[1];
    const float* wsim = (const float*)d_in[2];
    const float* W1s  = (const float*)d_in[3];
    const float* b1s  = (const float*)d_in[4];
    const float* W2s  = (const float*)d_in[5];
    const float* b2s  = (const float*)d_in[6];
    const float* W1e  = (const float*)d_in[7];
    const float* b1e  = (const float*)d_in[8];
    const float* W2e  = (const float*)d_in[9];
    const float* b2e  = (const float*)d_in[10];
    const float* Wb   = (const float*)d_in[11];

    char* ws = (char*)d_ws;
    float*  qw2  = (float*)(ws + OFF_QW2);
    float*  mrow = (float*)(ws + OFF_MROW);
    float*  q2c  = (float*)(ws + OFF_Q2C);
    float*  c2q  = (float*)(ws + OFF_C2Q);
    bf16_t* xb   = (bf16_t*)(ws + OFF_XB);
    bf16_t* hbuf = (bf16_t*)(ws + OFF_HBUF);
    bf16_t* W1st = (bf16_t*)(ws + OFF_W1ST);
    bf16_t* W2st = (bf16_t*)(ws + OFF_W2ST);
    bf16_t* W1et = (bf16_t*)(ws + OFF_W1ET);
    bf16_t* W2et = (bf16_t*)(ws + OFF_W2ET);
    bf16_t* T    = (bf16_t*)(ws + OFF_T);
    bf16_t* s1   = (bf16_t*)(ws + OFF_S1);
    bf16_t* e1   = (bf16_t*)(ws + OFF_E1);
    bf16_t* Wbt  = (bf16_t*)(ws + OFF_WBT);

    // weight prep + attention front-end
    k_qw2<<<256, 256, 0, stream>>>(ques, wsim, qw2);
    k_wtrans<<<dim3(32, 16), 256, 0, stream>>>(W1s, W1st, 1024, 512);
    k_wtrans<<<dim3(16, 32), 256, 0, stream>>>(W2s, W2st, 512, 1024);
    k_wtrans<<<dim3(32, 16), 256, 0, stream>>>(W1e, W1et, 1024, 512);
    k_wtrans<<<dim3(16, 32), 256, 0, stream>>>(W2e, W2et, 512, 1024);
    k_wb<<<3 * NP, 256, 0, stream>>>(Wb, Wbt);
    k_attn<<<Bsz * 32, 256, 0, stream>>>(ctx, ques, wsim, qw2, c2q, mrow);
    k_q2c<<<Bsz, 256, 0, stream>>>(ctx, mrow, q2c);
    k_buildx<<<NROW, 256, 0, stream>>>(ctx, c2q, q2c, xb);
    k_initse<<<1024, 256, 0, stream>>>(s1, e1);

    // FFW start: hbuf = relu(x@W1s + b1s); s1 = hbuf@W2s + b2s
    gemm_nt<0><<<dim3(64, 4, 1), 256, 0, stream>>>(xb, W1st, b1s, hbuf, 1024, 1024, 1024, 0, 0);
    gemm_nt<1><<<dim3(64, 8, 1), 256, 0, stream>>>(hbuf, W2st, b2s, s1, 512, 512, 512, 0, 0);
    // FFW end
    gemm_nt<0><<<dim3(64, 4, 1), 256, 0, stream>>>(xb, W1et, b1e, hbuf, 1024, 1024, 1024, 0, 0);
    gemm_nt<1><<<dim3(64, 8, 1), 256, 0, stream>>>(hbuf, W2et, b2e, e1, 512, 512, 512, 0, 0);
    // T[b][y*3+c][i] = sum_j e1[b,y,j] * Wb[i,c,j]
    gemm_nt<2><<<dim3(64, 9, 3), 256, 0, stream>>>(e1, Wbt, nullptr, T, KP, KP, KP,
                                                   0, (long)NP * KP);
    // out[b,x,y,c] = sum_i s1[b,x,i] * T[b][y*3+c][i]
    gemm_nt<3><<<dim3(4, 12, Bsz), 256, 0, stream>>>(s1, T, nullptr, d_out, KP, KP, KP,
                                                     (long)LCc * KP, (long)YC * KP);
}

// Round 2
// 358.619 us; speedup vs baseline: 1.0021x; 1.0021x over previous
//
#include <hip/hip_runtime.h>
#include <hip/hip_bf16.h>
#include <math.h>

typedef __bf16 bf16_t;
typedef bf16_t bf16x4 __attribute__((ext_vector_type(4)));
typedef bf16_t bf16x8 __attribute__((ext_vector_type(8)));
typedef float f32x4 __attribute__((ext_vector_type(4)));

#define Bsz 16
#define LCc 512
#define LQq 64
#define Hd 256
#define Dd 1024
#define DFFd 512
#define DP1 1025
#define KP 1152      // padded K for s1/e1/T cols/Wbt cols (18*64)
#define NT 18        // K tiles of 64
#define NIT 9        // NT/2
#define NP 1280      // padded row count for Wbt i-dim (5*256)
#define NROW 8192    // B*LC
#define YC 1536      // LC*3

// ---- workspace layout (bytes). T aliases the early-dead region. ----
#define OFF_T    0L
#define OFF_QW2  0L
#define OFF_MROW 4096L
#define OFF_Q2C  (OFF_MROW + 32768L)
#define OFF_C2Q  (OFF_Q2C + 16384L)
#define OFF_XB   (OFF_C2Q + 8388608L)
#define OFF_HBUF (OFF_XB + 16777216L)
#define OFF_W1ST (OFF_HBUF + 8388608L)
#define OFF_W2ST (OFF_W1ST + 1048576L)
#define OFF_W1ET (OFF_W2ST + 1048576L)
#define OFF_W2ET (OFF_W1ET + 1048576L)
// T size = 16*1536*1152*2 = 56623104 bytes
#define OFF_S1   56623104L
#define OFF_E1   (OFF_S1 + 18874368L)
#define OFF_WBT  (OFF_E1 + 18874368L)
// end = OFF_WBT + 3*1280*1152*2 = 103219200

static __device__ __forceinline__ void gload_lds16(const void* g, void* l) {
    __builtin_amdgcn_global_load_lds(
        (const __attribute__((address_space(1))) void*)g,
        (__attribute__((address_space(3))) void*)l, 16, 0, 0);
}

// ---------- qw2[b,j] = dot(ques[b,j,:], w2) ----------
__global__ __launch_bounds__(256) void k_qw2(const float* __restrict__ ques,
                                             const float* __restrict__ wsim,
                                             float* __restrict__ qw2) {
    int row = blockIdx.x * 4 + (threadIdx.x >> 6);
    int lane = threadIdx.x & 63;
    float4 q = *(const float4*)&ques[(long)row * Hd + lane * 4];
    float4 w = *(const float4*)&wsim[Hd + lane * 4];
    float p = q.x * w.x + q.y * w.y + q.z * w.z + q.w * w.w;
#pragma unroll
    for (int o = 32; o >= 1; o >>= 1) p += __shfl_xor(p, o, 64);
    if (lane == 0) qw2[row] = p;
}

// ---------- weight transpose f32 [K][N] -> bf16 [N][K] ----------
__global__ __launch_bounds__(256) void k_wtrans(const float* __restrict__ in,
                                                bf16_t* __restrict__ out,
                                                int K, int N) {
    __shared__ float tile[32][33];
    int k0 = blockIdx.x * 32, n0 = blockIdx.y * 32;
    int r = threadIdx.x >> 5, c = threadIdx.x & 31;
#pragma unroll
    for (int rr = 0; rr < 32; rr += 8)
        tile[r + rr][c] = in[(long)(k0 + r + rr) * N + n0 + c];
    __syncthreads();
#pragma unroll
    for (int rr = 0; rr < 32; rr += 8)
        out[(long)(n0 + r + rr) * K + k0 + c] = (bf16_t)tile[c][r + rr];
}

// ---------- Wbt[c][i][j] = Wb[i,c,j], bf16, zero-padded to [3][1280][1152] ----------
__global__ __launch_bounds__(256) void k_wb(const float* __restrict__ Wb,
                                            bf16_t* __restrict__ Wbt) {
    int rowz = blockIdx.x;          // c*1280 + i
    int c = rowz / NP, i = rowz % NP;
    int tid = threadIdx.x;
    bf16_t* orow = Wbt + (long)rowz * KP;
#pragma unroll
    for (int p = 0; p < 2; p++) {
        int j4 = tid + p * 256;
        if (j4 < KP / 4) {
            int j = j4 * 4;
            float x = 0.f, y = 0.f, z = 0.f, w = 0.f;
            if (i < DP1) {
                const float* src = Wb + ((long)i * 3 + c) * DP1 + j;
                if (j + 0 < DP1) x = src[0];
                if (j + 1 < DP1) y = src[1];
                if (j + 2 < DP1) z = src[2];
                if (j + 3 < DP1) w = src[3];
            }
            bf16x4 bv = {(bf16_t)x, (bf16_t)y, (bf16_t)z, (bf16_t)w};
            *(bf16x4*)&orow[j] = bv;
        }
    }
}

// ---------- init ones/zero pad cols [1024..1151] of s1,e1 ----------
__global__ __launch_bounds__(256) void k_initse(bf16_t* __restrict__ s1,
                                                bf16_t* __restrict__ e1) {
    int idx = blockIdx.x * 256 + threadIdx.x;   // 8192*128
    long r = idx >> 7; int cc = idx & 127;
    bf16_t v = (bf16_t)(cc == 0 ? 1.0f : 0.0f);
    s1[r * KP + 1024 + cc] = v;
    e1[r * KP + 1024 + cc] = v;
}

// ---------- attention: sim -> softmax_j -> c2q, rowmax -> mrow ----------
__global__ __launch_bounds__(256) void k_attn(const float* __restrict__ ctx,
                                              const float* __restrict__ ques,
                                              const float* __restrict__ wsim,
                                              const float* __restrict__ qw2,
                                              float* __restrict__ c2q,
                                              float* __restrict__ mrow) {
    __shared__ bf16x4 qlds[LQq * 64];
    __shared__ float cw3s[4][Hd];
    __shared__ float awave[4][LQq];
    int b = blockIdx.x >> 5;
    int itile = blockIdx.x & 31;
    int tid = threadIdx.x, wid = tid >> 6, lane = tid & 63;
#pragma unroll
    for (int p = 0; p < 16; p++) {
        int s = tid + p * 256;
        int j = s >> 6, h4s = s & 63;
        int h4 = h4s ^ (j & 15);
        float4 v = *(const float4*)&ques[((long)b * LQq + j) * Hd + h4 * 4];
        bf16x4 bv = {(bf16_t)v.x, (bf16_t)v.y, (bf16_t)v.z, (bf16_t)v.w};
        qlds[s] = bv;
    }
    float qw2r = qw2[b * LQq + lane];
    float4 w1v = *(const float4*)&wsim[lane * 4];
    float4 w3v = *(const float4*)&wsim[2 * Hd + lane * 4];
    __syncthreads();
    for (int rr = 0; rr < 4; rr++) {
        int i = itile * 16 + wid * 4 + rr;
        float4 cv = *(const float4*)&ctx[((long)b * LCc + i) * Hd + lane * 4];
        float cw1p = cv.x * w1v.x + cv.y * w1v.y + cv.z * w1v.z + cv.w * w1v.w;
        float4 c3;
        c3.x = cv.x * w3v.x; c3.y = cv.y * w3v.y;
        c3.z = cv.z * w3v.z; c3.w = cv.w * w3v.w;
        *(float4*)&cw3s[wid][lane * 4] = c3;
#pragma unroll
        for (int o = 32; o >= 1; o >>= 1) cw1p += __shfl_xor(cw1p, o, 64);
        __syncthreads();
        float s = cw1p + qw2r;
#pragma unroll 8
        for (int h4 = 0; h4 < 64; h4++) {
            float4 c3v = *(const float4*)&cw3s[wid][h4 * 4];
            bf16x4 qb = qlds[lane * 64 + (h4 ^ (lane & 15))];
            s += c3v.x * (float)qb[0] + c3v.y * (float)qb[1]
               + c3v.z * (float)qb[2] + c3v.w * (float)qb[3];
        }
        float mx = s;
#pragma unroll
        for (int o = 32; o >= 1; o >>= 1) mx = fmaxf(mx, __shfl_xor(mx, o, 64));
        if (lane == 0) mrow[b * LCc + i] = mx;
        float pe = __expf(s - mx);
        float den = pe;
#pragma unroll
        for (int o = 32; o >= 1; o >>= 1) den += __shfl_xor(den, o, 64);
        awave[wid][lane] = pe / den;
        __syncthreads();
        float4 accv = {0.f, 0.f, 0.f, 0.f};
#pragma unroll 8
        for (int j = 0; j < 64; j++) {
            float aj = awave[wid][j];
            bf16x4 qb = qlds[j * 64 + (lane ^ (j & 15))];
            accv.x = fmaf(aj, (float)qb[0], accv.x);
            accv.y = fmaf(aj, (float)qb[1], accv.y);
            accv.z = fmaf(aj, (float)qb[2], accv.z);
            accv.w = fmaf(aj, (float)qb[3], accv.w);
        }
        *(float4*)&c2q[((long)b * LCc + i) * Hd + lane * 4] = accv;
        __syncthreads();
    }
}

// ---------- q2c[b,h] = sum_i softmax_i(mrow)[i] * ctx[b,i,h] ----------
__global__ __launch_bounds__(256) void k_q2c(const float* __restrict__ ctx,
                                             const float* __restrict__ mrow,
                                             float* __restrict__ q2c) {
    __shared__ float wbuf[LCc];
    __shared__ float red[8];
    int b = blockIdx.x, tid = threadIdx.x;
    float v0 = mrow[b * LCc + tid], v1 = mrow[b * LCc + 256 + tid];
    float m = fmaxf(v0, v1);
#pragma unroll
    for (int o = 32; o >= 1; o >>= 1) m = fmaxf(m, __shfl_xor(m, o, 64));
    if ((tid & 63) == 0) red[tid >> 6] = m;
    __syncthreads();
    float M = fmaxf(fmaxf(red[0], red[1]), fmaxf(red[2], red[3]));
    float e0 = __expf(v0 - M), e1v = __expf(v1 - M);
    float sm = e0 + e1v;
#pragma unroll
    for (int o = 32; o >= 1; o >>= 1) sm += __shfl_xor(sm, o, 64);
    if ((tid & 63) == 0) red[4 + (tid >> 6)] = sm;
    __syncthreads();
    float S = red[4] + red[5] + red[6] + red[7];
    wbuf[tid] = e0 / S;
    wbuf[tid + 256] = e1v / S;
    __syncthreads();
    float acc = 0.f;
#pragma unroll 8
    for (int i = 0; i < LCc; i++)
        acc = fmaf(wbuf[i], ctx[((long)b * LCc + i) * Hd + tid], acc);
    q2c[b * Hd + tid] = acc;
}

// ---------- x = [ctx, c2q, ctx*c2q, ctx*q2c] -> bf16 [8192][1024] ----------
__global__ __launch_bounds__(256) void k_buildx(const float* __restrict__ ctx,
                                                const float* __restrict__ c2q,
                                                const float* __restrict__ q2c,
                                                bf16_t* __restrict__ xb) {
    long r = blockIdx.x;
    int b = (int)(r >> 9);
    int tid = threadIdx.x;
    int sec = tid >> 6, h4 = tid & 63;
    float4 cv = *(const float4*)&ctx[r * Hd + h4 * 4];
    float4 v;
    if (sec == 0) {
        v = cv;
    } else if (sec == 1) {
        v = *(const float4*)&c2q[r * Hd + h4 * 4];
    } else if (sec == 2) {
        float4 q = *(const float4*)&c2q[r * Hd + h4 * 4];
        v.x = cv.x * q.x; v.y = cv.y * q.y; v.z = cv.z * q.z; v.w = cv.w * q.w;
    } else {
        float4 q = *(const float4*)&q2c[b * Hd + h4 * 4];
        v.x = cv.x * q.x; v.y = cv.y * q.y; v.z = cv.z * q.z; v.w = cv.w * q.w;
    }
    bf16x4 bv = {(bf16_t)v.x, (bf16_t)v.y, (bf16_t)v.z, (bf16_t)v.w};
    *(bf16x4*)&xb[r * Dd + sec * Hd + h4 * 4] = bv;
}

// ---------- bf16 NT GEMM (FFW): 128x128x32, 4 waves ----------
// MODE 0: +bias, relu, store bf16 ldc=512 (hbuf)
// MODE 1: +bias, store bf16 ldc=KP (s1/e1)
template <int MODE>
__global__ __launch_bounds__(256, 2) void gemm_nt(
    const bf16_t* __restrict__ A, const bf16_t* __restrict__ B,
    const float* __restrict__ bias, void* __restrict__ C,
    int K, int lda, int ldb) {
    __shared__ bf16_t As[128 * 32];
    __shared__ bf16_t Bs[128 * 32];
    int tid = threadIdx.x;
    int wid = tid >> 6, lane = tid & 63;
    const bf16_t* Ab = A + (long)blockIdx.x * 128 * lda;
    const bf16_t* Bb = B + (long)blockIdx.y * 128 * ldb;
    int wr = (wid >> 1) * 64, wc = (wid & 1) * 64;
    int fr = lane & 15, kg = lane >> 4;
    f32x4 acc[4][4] = {};
    for (int k0 = 0; k0 < K; k0 += 32) {
        __syncthreads();
#pragma unroll
        for (int p = 0; p < 2; p++) {
            int q = tid + p * 256;
            int row = q >> 2, cg = q & 3;
            gload_lds16(Ab + (long)row * lda + k0 + cg * 8, &As[q * 8]);
            gload_lds16(Bb + (long)row * ldb + k0 + cg * 8, &Bs[q * 8]);
        }
        __syncthreads();
        bf16x8 af[4], bq[4];
#pragma unroll
        for (int m = 0; m < 4; m++)
            af[m] = *(const bf16x8*)&As[(wr + m * 16 + fr) * 32 + kg * 8];
#pragma unroll
        for (int n = 0; n < 4; n++)
            bq[n] = *(const bf16x8*)&Bs[(wc + n * 16 + fr) * 32 + kg * 8];
#pragma unroll
        for (int m = 0; m < 4; m++)
#pragma unroll
            for (int n = 0; n < 4; n++)
                acc[m][n] = __builtin_amdgcn_mfma_f32_16x16x32_bf16(
                    af[m], bq[n], acc[m][n], 0, 0, 0);
    }
    int g4 = (lane >> 4) * 4;
#pragma unroll
    for (int m = 0; m < 4; m++) {
#pragma unroll
        for (int g = 0; g < 4; g++) {
            long r = (long)blockIdx.x * 128 + wr + m * 16 + g4 + g;
#pragma unroll
            for (int n = 0; n < 4; n++) {
                int col = blockIdx.y * 128 + wc + n * 16 + fr;
                float v = acc[m][n][g] + bias[col];
                if (MODE == 0) {
                    v = fmaxf(v, 0.f);
                    ((bf16_t*)C)[r * DFFd + col] = (bf16_t)v;
                } else {
                    ((bf16_t*)C)[r * KP + col] = (bf16_t)v;
                }
            }
        }
    }
}

// ---------- 256x256x64 8-phase counted-vmcnt GEMM (T2+T3+T4+T5, XCD swizzle) ----
// C = A[M,KP] * B[N,KP]^T, bf16 in, per-z slices.
// MODE 2: store bf16 T[(r*3+z)*KP + col], guard col<KP   (A=e1, B=Wbt, z=c in 0..2)
// MODE 3: store f32 out[z*512*1536 + r*1536 + col]       (A=s1, B=T,  z=b in 0..15)
template <int MODE>
__global__ __launch_bounds__(512) void gemm8(
    const bf16_t* __restrict__ A, const bf16_t* __restrict__ B,
    void* __restrict__ C, int nbx, int nby) {
    __shared__ char smem[131072];   // A: [0,64K) 2 bufs; B: [64K,128K) 2 bufs
    int tid = threadIdx.x;
    const int nz = (MODE == 2) ? 3 : Bsz;
    int nwg = nbx * nby * nz;
    int nper = nwg >> 3;            // grid sizes divisible by 8
    int wg = blockIdx.x;
    int wgid = (wg & 7) * nper + (wg >> 3);   // bijective XCD swizzle
    int z = wgid / (nbx * nby);
    int rem = wgid - z * nbx * nby;
    int by = rem / nbx, bx = rem - by * nbx;
    const bf16_t* At;
    const bf16_t* Bt;
    if (MODE == 2) {
        At = A + (long)bx * 256 * KP;
        Bt = B + ((long)z * NP + by * 256) * KP;
    } else {
        At = A + ((long)z * LCc + bx * 256) * KP;
        Bt = B + ((long)z * YC + by * 256) * KP;
    }
    int lane = tid & 63, wv = tid >> 6, wm = wv >> 2, wn = wv & 3;
    int fr = lane & 15, kg = lane >> 4;
    // staging address precompute: chunk q -> row=q>>3, c16=q&7; src c16 ^= row&7
    int row0 = tid >> 3, sc0 = (tid & 7) ^ (row0 & 7);
    int q1 = tid + 512;
    int row1 = q1 >> 3, sc1 = (q1 & 7) ^ (row1 & 7);

    auto STAGE = [&](int mat, int ht, int tile) {
        int ts = tile <= NT - 1 ? tile : NT - 1;   // clamp source (dest buf per schedule)
        int buf = tile & 1;
        const bf16_t* base = mat ? Bt : At;
        long rb = (long)ht * 128;
        const bf16_t* g0 = base + (rb + row0) * KP + ts * 64 + sc0 * 8;
        const bf16_t* g1 = base + (rb + row1) * KP + ts * 64 + sc1 * 8;
        char* l = smem + (mat ? 65536 : 0) + buf * 32768 + ht * 16384;
        gload_lds16(g0, l + tid * 16);
        gload_lds16(g1, l + 8192 + tid * 16);
    };
    auto RDA = [&](int buf, int h, int m, int kk) -> bf16x8 {
        int row = wm * 128 + h * 64 + m * 16 + fr;
        int c16 = kk * 4 + kg;
        int off = buf * 32768 + row * 128 + ((c16 ^ (row & 7)) << 4);
        return *(const bf16x8*)(smem + off);
    };
    auto RDB = [&](int buf, int v, int n, int kk) -> bf16x8 {
        int row = wn * 64 + v * 32 + n * 16 + fr;
        int c16 = kk * 4 + kg;
        int off = 65536 + buf * 32768 + row * 128 + ((c16 ^ (row & 7)) << 4);
        return *(const bf16x8*)(smem + off);
    };

    f32x4 acc[8][4] = {};

    // prologue: T0 fully + T1 A-halves; leave 4 loads (T1 A0,A1) in flight
    STAGE(0, 0, 0); STAGE(0, 1, 0); STAGE(1, 0, 0); STAGE(1, 1, 0);
    STAGE(0, 0, 1); STAGE(0, 1, 1);
    asm volatile("s_waitcnt vmcnt(4)" ::: "memory");
    __builtin_amdgcn_s_barrier();

    auto doTile = [&](int buf, int sB, int sA, bool boundary) {
        bf16x8 aL[4][2], aH[4][2], bE[2][2], bO[2][2];
        // ---- phase a: read A-h0 + B-v0, stage B0(sB), MFMA quad (h0,v0)
#pragma unroll
        for (int m = 0; m < 4; m++)
#pragma unroll
            for (int k = 0; k < 2; k++) aL[m][k] = RDA(buf, 0, m, k);
#pragma unroll
        for (int n = 0; n < 2; n++)
#pragma unroll
            for (int k = 0; k < 2; k++) bE[n][k] = RDB(buf, 0, n, k);
        STAGE(1, 0, sB);
        __builtin_amdgcn_s_barrier();
        __builtin_amdgcn_s_setprio(1);
#pragma unroll
        for (int m = 0; m < 4; m++)
#pragma unroll
            for (int n = 0; n < 2; n++)
#pragma unroll
                for (int k = 0; k < 2; k++)
                    acc[m][n] = __builtin_amdgcn_mfma_f32_16x16x32_bf16(
                        aL[m][k], bE[n][k], acc[m][n], 0, 0, 0);
        __builtin_amdgcn_s_setprio(0);
        __builtin_amdgcn_s_barrier();
        // ---- phase b: read B-v1, stage B1(sB), MFMA quad (h0,v1)
#pragma unroll
        for (int n = 0; n < 2; n++)
#pragma unroll
            for (int k = 0; k < 2; k++) bO[n][k] = RDB(buf, 1, n, k);
        STAGE(1, 1, sB);
        __builtin_amdgcn_s_barrier();
        __builtin_amdgcn_s_setprio(1);
#pragma unroll
        for (int m = 0; m < 4; m++)
#pragma unroll
            for (int n = 0; n < 2; n++)
#pragma unroll
                for (int k = 0; k < 2; k++)
                    acc[m][2 + n] = __builtin_amdgcn_mfma_f32_16x16x32_bf16(
                        aL[m][k], bO[n][k], acc[m][2 + n], 0, 0, 0);
        __builtin_amdgcn_s_setprio(0);
        __builtin_amdgcn_s_barrier();
        // ---- phase c: read A-h1, stage A0(sA), MFMA quad (h1,v0)
#pragma unroll
        for (int m = 0; m < 4; m++)
#pragma unroll
            for (int k = 0; k < 2; k++) aH[m][k] = RDA(buf, 1, m, k);
        STAGE(0, 0, sA);
        __builtin_amdgcn_s_barrier();
        __builtin_amdgcn_s_setprio(1);
#pragma unroll
        for (int m = 0; m < 4; m++)
#pragma unroll
            for (int n = 0; n < 2; n++)
#pragma unroll
                for (int k = 0; k < 2; k++)
                    acc[4 + m][n] = __builtin_amdgcn_mfma_f32_16x16x32_bf16(
                        aH[m][k], bE[n][k], acc[4 + m][n], 0, 0, 0);
        __builtin_amdgcn_s_setprio(0);
        __builtin_amdgcn_s_barrier();
        // ---- phase d: stage A1(sA), MFMA quad (h1,v1), counted vmcnt, barrier
        STAGE(0, 1, sA);
        __builtin_amdgcn_s_barrier();
        __builtin_amdgcn_s_setprio(1);
#pragma unroll
        for (int m = 0; m < 4; m++)
#pragma unroll
            for (int n = 0; n < 2; n++)
#pragma unroll
                for (int k = 0; k < 2; k++)
                    acc[4 + m][2 + n] = __builtin_amdgcn_mfma_f32_16x16x32_bf16(
                        aH[m][k], bO[n][k], acc[4 + m][2 + n], 0, 0, 0);
        __builtin_amdgcn_s_setprio(0);
        asm volatile("s_waitcnt vmcnt(4)" ::: "memory");
        __builtin_amdgcn_s_barrier();
        (void)boundary;
    };

    for (int it = 0; it < NIT; ++it) {
        int t = 2 * it;
        doTile(0, t + 1, t + 2, false);   // tile t   (even -> buf 0)
        doTile(1, t + 2, t + 3, true);    // tile t+1 (odd  -> buf 1)
    }

    // epilogue
#pragma unroll
    for (int mf = 0; mf < 8; mf++) {
#pragma unroll
        for (int g = 0; g < 4; g++) {
            long r = (long)bx * 256 + wm * 128 + mf * 16 + kg * 4 + g;
#pragma unroll
            for (int nf = 0; nf < 4; nf++) {
                int col = by * 256 + wn * 64 + nf * 16 + fr;
                float v = acc[mf][nf][g];
                if (MODE == 2) {
                    if (col < KP)
                        ((bf16_t*)C)[(r * 3 + z) * (long)KP + col] = (bf16_t)v;
                } else {
                    ((float*)C)[(long)z * (LCc * YC) + r * YC + col] = v;
                }
            }
        }
    }
}

extern "C" void kernel_launch(void* const* d_in, const int* in_sizes, int n_in,
                              void* d_out, int out_size, void* d_ws, size_t ws_size,
                              hipStream_t stream) {
    const float* ctx  = (const float*)d_in[0];
    const float* ques = (const float*)d_in[1];
    const float* wsim = (const float*)d_in[2];
    const float* W1s  = (const float*)d_in[3];
    const float* b1s  = (const float*)d_in[4];
    const float* W2s  = (const float*)d_in[5];
    const float* b2s  = (const float*)d_in[6];
    const float* W1e  = (const float*)d_in[7];
    const float* b1e  = (const float*)d_in[8];
    const float* W2e  = (const float*)d_in[9];
    const float* b2e  = (const float*)d_in[10];
    const float* Wb   = (const float*)d_in[11];

    char* ws = (char*)d_ws;
    float*  qw2  = (float*)(ws + OFF_QW2);
    float*  mrow = (float*)(ws + OFF_MROW);
    float*  q2c  = (float*)(ws + OFF_Q2C);
    float*  c2q  = (float*)(ws + OFF_C2Q);
    bf16_t* xb   = (bf16_t*)(ws + OFF_XB);
    bf16_t* hbuf = (bf16_t*)(ws + OFF_HBUF);
    bf16_t* W1st = (bf16_t*)(ws + OFF_W1ST);
    bf16_t* W2st = (bf16_t*)(ws + OFF_W2ST);
    bf16_t* W1et = (bf16_t*)(ws + OFF_W1ET);
    bf16_t* W2et = (bf16_t*)(ws + OFF_W2ET);
    bf16_t* T    = (bf16_t*)(ws + OFF_T);
    bf16_t* s1   = (bf16_t*)(ws + OFF_S1);
    bf16_t* e1   = (bf16_t*)(ws + OFF_E1);
    bf16_t* Wbt  = (bf16_t*)(ws + OFF_WBT);

    // weight prep + attention front-end
    k_qw2<<<256, 256, 0, stream>>>(ques, wsim, qw2);
    k_wtrans<<<dim3(32, 16), 256, 0, stream>>>(W1s, W1st, 1024, 512);
    k_wtrans<<<dim3(16, 32), 256, 0, stream>>>(W2s, W2st, 512, 1024);
    k_wtrans<<<dim3(32, 16), 256, 0, stream>>>(W1e, W1et, 1024, 512);
    k_wtrans<<<dim3(16, 32), 256, 0, stream>>>(W2e, W2et, 512, 1024);
    k_wb<<<3 * NP, 256, 0, stream>>>(Wb, Wbt);
    k_attn<<<Bsz * 32, 256, 0, stream>>>(ctx, ques, wsim, qw2, c2q, mrow);
    k_q2c<<<Bsz, 256, 0, stream>>>(ctx, mrow, q2c);
    k_buildx<<<NROW, 256, 0, stream>>>(ctx, c2q, q2c, xb);
    k_initse<<<4096, 256, 0, stream>>>(s1, e1);

    // FFW start: hbuf = relu(x@W1s + b1s); s1 = hbuf@W2s + b2s
    gemm_nt<0><<<dim3(64, 4), 256, 0, stream>>>(xb, W1st, b1s, hbuf, 1024, 1024, 1024);
    gemm_nt<1><<<dim3(64, 8), 256, 0, stream>>>(hbuf, W2st, b2s, s1, 512, 512, 512);
    // FFW end
    gemm_nt<0><<<dim3(64, 4), 256, 0, stream>>>(xb, W1et, b1e, hbuf, 1024, 1024, 1024);
    gemm_nt<1><<<dim3(64, 8), 256, 0, stream>>>(hbuf, W2et, b2e, e1, 512, 512, 512);
    // T[b][y*3+c][i] = sum_j e1[b,y,j] * Wb[i,c,j]   (8-phase 256^2)
    gemm8<2><<<480, 512, 0, stream>>>(e1, Wbt, T, 32, 5);
    // out[b,x,y,c] = sum_i s1[b,x,i] * T[b][y*3+c][i] (8-phase 256^2)
    gemm8<3><<<192, 512, 0, stream>>>(s1, T, d_out, 2, 6);
}

// Round 5
// 314.748 us; speedup vs baseline: 1.1418x; 1.1394x over previous
//
#include <hip/hip_runtime.h>
#include <hip/hip_bf16.h>
#include <math.h>

typedef __bf16 bf16_t;
typedef bf16_t bf16x4 __attribute__((ext_vector_type(4)));
typedef bf16_t bf16x8 __attribute__((ext_vector_type(8)));
typedef float f32x4 __attribute__((ext_vector_type(4)));

#define Bsz 16
#define LCc 512
#define LQq 64
#define Hd 256
#define Dd 1024
#define DFFd 512
#define DP1 1025
#define KP 1152      // padded contraction dim, 18 tiles of 64 (EVEN -> no tail)
#define NTT 18
#define NROW 8192
#define YC 1536

// ---- workspace layout (bytes). T aliases the early-dead region. ----
#define OFF_T    0L          // 24576*1152*2 = 56623104
#define OFF_QW2  0L
#define OFF_MROW 4096L
#define OFF_Q2C  36864L
#define OFF_C2Q  53248L      // 8388608
#define OFF_XB   8441856L    // 16777216
#define OFF_HBUF 25219072L   // 16777216
#define OFF_W1C  41996288L   // 2097152
#define OFF_W2C  44093440L   // 2097152 (ends 46190592 < 56623104)
#define OFF_S1   56623104L   // 18874368
#define OFF_E1   75497472L   // 18874368
#define OFF_WBT  94371840L   // 3072*1152*2 = 7077888 ; end = 101449728

static __device__ __forceinline__ void gload_lds16(const void* g, void* l) {
    __builtin_amdgcn_global_load_lds(
        (const __attribute__((address_space(1))) void*)g,
        (__attribute__((address_space(3))) void*)l, 16, 0, 0);
}

// ---------- qw2[b,j] = dot(ques[b,j,:], w2) ----------
__global__ __launch_bounds__(256) void k_qw2(const float* __restrict__ ques,
                                             const float* __restrict__ wsim,
                                             float* __restrict__ qw2) {
    int row = blockIdx.x * 4 + (threadIdx.x >> 6);
    int lane = threadIdx.x & 63;
    float4 q = *(const float4*)&ques[(long)row * Hd + lane * 4];
    float4 w = *(const float4*)&wsim[Hd + lane * 4];
    float p = q.x * w.x + q.y * w.y + q.z * w.z + q.w * w.w;
#pragma unroll
    for (int o = 32; o >= 1; o >>= 1) p += __shfl_xor(p, o, 64);
    if (lane == 0) qw2[row] = p;
}

// ---------- weight transpose f32 [K][N] -> bf16 [N][K] ----------
__global__ __launch_bounds__(256) void k_wtrans(const float* __restrict__ in,
                                                bf16_t* __restrict__ out,
                                                int K, int N) {
    __shared__ float tile[32][33];
    int k0 = blockIdx.x * 32, n0 = blockIdx.y * 32;
    int r = threadIdx.x >> 5, c = threadIdx.x & 31;
#pragma unroll
    for (int rr = 0; rr < 32; rr += 8)
        tile[r + rr][c] = in[(long)(k0 + r + rr) * N + n0 + c];
    __syncthreads();
#pragma unroll
    for (int rr = 0; rr < 32; rr += 8)
        out[(long)(n0 + r + rr) * K + k0 + c] = (bf16_t)tile[c][r + rr];
}

// ---------- Wbt[c*1024+i][j] = Wb[i,c,j], bf16, [3072][1152], cols>=1025 zero ----------
__global__ __launch_bounds__(256) void k_wb(const float* __restrict__ Wb,
                                            bf16_t* __restrict__ Wbt) {
    int rw = blockIdx.x;            // c*1024 + i
    int c = rw >> 10, i = rw & 1023;
    int tid = threadIdx.x;
    const float* src = Wb + ((long)i * 3 + c) * DP1;
    bf16_t* orow = Wbt + (long)rw * KP;
#pragma unroll
    for (int p = 0; p < 2; p++) {
        int j4 = tid + p * 256;
        if (j4 < KP / 4) {
            int j = j4 * 4;
            float x = (j + 0 < DP1) ? src[j + 0] : 0.f;
            float y = (j + 1 < DP1) ? src[j + 1] : 0.f;
            float z = (j + 2 < DP1) ? src[j + 2] : 0.f;
            float w = (j + 3 < DP1) ? src[j + 3] : 0.f;
            bf16x4 bv = {(bf16_t)x, (bf16_t)y, (bf16_t)z, (bf16_t)w};
            *(bf16x4*)&orow[j] = bv;
        }
    }
}

// ---------- init cols [1024..1151] of s1,e1: col1024=1, rest 0 ----------
__global__ __launch_bounds__(256) void k_initse(bf16_t* __restrict__ s1,
                                                bf16_t* __restrict__ e1) {
    int idx = blockIdx.x * 256 + threadIdx.x;   // 8192*128
    long r = idx >> 7; int cc = idx & 127;
    bf16_t v = (bf16_t)(cc == 0 ? 1.0f : 0.0f);
    s1[r * KP + 1024 + cc] = v;
    e1[r * KP + 1024 + cc] = v;
}

// ---------- attention: sim -> softmax_j -> c2q, rowmax -> mrow ----------
__global__ __launch_bounds__(256) void k_attn(const float* __restrict__ ctx,
                                              const float* __restrict__ ques,
                                              const float* __restrict__ wsim,
                                              const float* __restrict__ qw2,
                                              float* __restrict__ c2q,
                                              float* __restrict__ mrow) {
    __shared__ bf16x4 qlds[LQq * 64];
    __shared__ float cw3s[4][Hd];
    __shared__ float awave[4][LQq];
    int b = blockIdx.x >> 5;
    int itile = blockIdx.x & 31;
    int tid = threadIdx.x, wid = tid >> 6, lane = tid & 63;
#pragma unroll
    for (int p = 0; p < 16; p++) {
        int s = tid + p * 256;
        int j = s >> 6, h4s = s & 63;
        int h4 = h4s ^ (j & 15);
        float4 v = *(const float4*)&ques[((long)b * LQq + j) * Hd + h4 * 4];
        bf16x4 bv = {(bf16_t)v.x, (bf16_t)v.y, (bf16_t)v.z, (bf16_t)v.w};
        qlds[s] = bv;
    }
    float qw2r = qw2[b * LQq + lane];
    float4 w1v = *(const float4*)&wsim[lane * 4];
    float4 w3v = *(const float4*)&wsim[2 * Hd + lane * 4];
    __syncthreads();
    for (int rr = 0; rr < 4; rr++) {
        int i = itile * 16 + wid * 4 + rr;
        float4 cv = *(const float4*)&ctx[((long)b * LCc + i) * Hd + lane * 4];
        float cw1p = cv.x * w1v.x + cv.y * w1v.y + cv.z * w1v.z + cv.w * w1v.w;
        float4 c3;
        c3.x = cv.x * w3v.x; c3.y = cv.y * w3v.y;
        c3.z = cv.z * w3v.z; c3.w = cv.w * w3v.w;
        *(float4*)&cw3s[wid][lane * 4] = c3;
#pragma unroll
        for (int o = 32; o >= 1; o >>= 1) cw1p += __shfl_xor(cw1p, o, 64);
        __syncthreads();
        float s = cw1p + qw2r;
#pragma unroll 8
        for (int h4 = 0; h4 < 64; h4++) {
            float4 c3v = *(const float4*)&cw3s[wid][h4 * 4];
            bf16x4 qb = qlds[lane * 64 + (h4 ^ (lane & 15))];
            s += c3v.x * (float)qb[0] + c3v.y * (float)qb[1]
               + c3v.z * (float)qb[2] + c3v.w * (float)qb[3];
        }
        float mx = s;
#pragma unroll
        for (int o = 32; o >= 1; o >>= 1) mx = fmaxf(mx, __shfl_xor(mx, o, 64));
        if (lane == 0) mrow[b * LCc + i] = mx;
        float pe = __expf(s - mx);
        float den = pe;
#pragma unroll
        for (int o = 32; o >= 1; o >>= 1) den += __shfl_xor(den, o, 64);
        awave[wid][lane] = pe / den;
        __syncthreads();
        float4 accv = {0.f, 0.f, 0.f, 0.f};
#pragma unroll 8
        for (int j = 0; j < 64; j++) {
            float aj = awave[wid][j];
            bf16x4 qb = qlds[j * 64 + (lane ^ (j & 15))];
            accv.x = fmaf(aj, (float)qb[0], accv.x);
            accv.y = fmaf(aj, (float)qb[1], accv.y);
            accv.z = fmaf(aj, (float)qb[2], accv.z);
            accv.w = fmaf(aj, (float)qb[3], accv.w);
        }
        *(float4*)&c2q[((long)b * LCc + i) * Hd + lane * 4] = accv;
        __syncthreads();
    }
}

// ---------- q2c: 128 blocks = 16 b x 8 h-chunks ----------
__global__ __launch_bounds__(256) void k_q2c(const float* __restrict__ ctx,
                                             const float* __restrict__ mrow,
                                             float* __restrict__ q2c) {
    __shared__ float wbuf[LCc];
    __shared__ float red[8];
    __shared__ float part[8][32];
    int blk = blockIdx.x;
    int b = blk >> 3, hc = blk & 7;
    int tid = threadIdx.x;
    float v0 = mrow[b * LCc + tid], v1 = mrow[b * LCc + 256 + tid];
    float m = fmaxf(v0, v1);
#pragma unroll
    for (int o = 32; o >= 1; o >>= 1) m = fmaxf(m, __shfl_xor(m, o, 64));
    if ((tid & 63) == 0) red[tid >> 6] = m;
    __syncthreads();
    float M = fmaxf(fmaxf(red[0], red[1]), fmaxf(red[2], red[3]));
    float e0 = __expf(v0 - M), e1v = __expf(v1 - M);
    float sm = e0 + e1v;
#pragma unroll
    for (int o = 32; o >= 1; o >>= 1) sm += __shfl_xor(sm, o, 64);
    if ((tid & 63) == 0) red[4 + (tid >> 6)] = sm;
    __syncthreads();
    float S = red[4] + red[5] + red[6] + red[7];
    wbuf[tid] = e0 / S;
    wbuf[tid + 256] = e1v / S;
    __syncthreads();
    int ig = tid >> 5, h31 = tid & 31;
    int h = hc * 32 + h31;
    float acc = 0.f;
#pragma unroll 4
    for (int ii = 0; ii < 64; ii++) {
        int i = ig * 64 + ii;
        acc = fmaf(wbuf[i], ctx[((long)b * LCc + i) * Hd + h], acc);
    }
    part[ig][h31] = acc;
    __syncthreads();
    if (tid < 32) {
        float s = 0.f;
#pragma unroll
        for (int k = 0; k < 8; k++) s += part[k][tid];
        q2c[b * Hd + hc * 32 + tid] = s;
    }
}

// ---------- x = [ctx, c2q, ctx*c2q, ctx*q2c] -> bf16 [8192][1024] ----------
__global__ __launch_bounds__(256) void k_buildx(const float* __restrict__ ctx,
                                                const float* __restrict__ c2q,
                                                const float* __restrict__ q2c,
                                                bf16_t* __restrict__ xb) {
    long r = blockIdx.x;
    int b = (int)(r >> 9);
    int tid = threadIdx.x;
    int sec = tid >> 6, h4 = tid & 63;
    float4 cv = *(const float4*)&ctx[r * Hd + h4 * 4];
    float4 v;
    if (sec == 0) {
        v = cv;
    } else if (sec == 1) {
        v = *(const float4*)&c2q[r * Hd + h4 * 4];
    } else if (sec == 2) {
        float4 q = *(const float4*)&c2q[r * Hd + h4 * 4];
        v.x = cv.x * q.x; v.y = cv.y * q.y; v.z = cv.z * q.z; v.w = cv.w * q.w;
    } else {
        float4 q = *(const float4*)&q2c[b * Hd + h4 * 4];
        v.x = cv.x * q.x; v.y = cv.y * q.y; v.z = cv.z * q.z; v.w = cv.w * q.w;
    }
    bf16x4 bv = {(bf16_t)v.x, (bf16_t)v.y, (bf16_t)v.z, (bf16_t)v.w};
    *(bf16x4*)&xb[r * Dd + sec * Hd + h4 * 4] = bv;
}

// ---------- g-column + T pad-zero: T[(r*3+c)*KP+1024] = e1[r,:].Wb[1024,c,:]; cols>1024 = 0 ----------
__global__ __launch_bounds__(256) void k_gcol(const bf16_t* __restrict__ e1,
                                              const float* __restrict__ Wb,
                                              bf16_t* __restrict__ T) {
    int tid = threadIdx.x;
    int wv = tid >> 6, lane = tid & 63;
    long r = (long)blockIdx.x * 4 + wv;
    bf16x8 ea = *(const bf16x8*)&e1[r * KP + lane * 16];
    bf16x8 eb = *(const bf16x8*)&e1[r * KP + lane * 16 + 8];
    const float* wr0 = Wb + (long)3072 * DP1;   // row block i=1024
#pragma unroll
    for (int c = 0; c < 3; c++) {
        const float* wr = wr0 + (long)c * DP1 + lane * 16;
        float acc = 0.f;
#pragma unroll
        for (int k = 0; k < 8; k++) {
            acc = fmaf((float)ea[k], wr[k], acc);
            acc = fmaf((float)eb[k], wr[8 + k], acc);
        }
#pragma unroll
        for (int o = 32; o >= 1; o >>= 1) acc += __shfl_xor(acc, o, 64);
        long rowb = (r * 3 + c) * (long)KP;
        if (lane == 0)
            T[rowb + 1024] = (bf16_t)(acc + wr0[(long)c * DP1 + 1024]);
        for (int jj = 1025 + lane; jj < KP; jj += 64)
            T[rowb + jj] = (bf16_t)0.f;
    }
}

// ---------- bf16 NT GEMM (FFW): 128x128x32, 4 waves ----------
// MODE 0: C0=hbuf[8192][1024], bias col<512 ? b0 : b1, relu
// MODE 1: z-batched (grid.z=2): A col-offset z*512, B=W2cat+z*1024*512, C=(z?C1:C0), ld KP
template <int MODE>
__global__ __launch_bounds__(256, 2) void gemm_nt(
    const bf16_t* __restrict__ A, const bf16_t* __restrict__ B,
    const float* __restrict__ bias0, const float* __restrict__ bias1,
    bf16_t* __restrict__ C0, bf16_t* __restrict__ C1) {
    const int K = (MODE == 0) ? 1024 : 512;
    const int lda = 1024;
    const int ldb = (MODE == 0) ? 1024 : 512;
    __shared__ bf16_t As[128 * 32];
    __shared__ bf16_t Bs[128 * 32];
    int tid = threadIdx.x;
    int wid = tid >> 6, lane = tid & 63;
    int z = (MODE == 1) ? blockIdx.z : 0;
    const bf16_t* Ab = A + (long)blockIdx.x * 128 * lda + z * 512;
    const bf16_t* Bb = B + (long)z * 1024 * 512 + (long)blockIdx.y * 128 * ldb;
    int wr = (wid >> 1) * 64, wc = (wid & 1) * 64;
    int fr = lane & 15, kg = lane >> 4;
    f32x4 acc[4][4] = {};
    for (int k0 = 0; k0 < K; k0 += 32) {
        __syncthreads();
#pragma unroll
        for (int p = 0; p < 2; p++) {
            int q = tid + p * 256;
            int row = q >> 2, cg = q & 3;
            gload_lds16(Ab + (long)row * lda + k0 + cg * 8, &As[q * 8]);
            gload_lds16(Bb + (long)row * ldb + k0 + cg * 8, &Bs[q * 8]);
        }
        __syncthreads();
        bf16x8 af[4], bq[4];
#pragma unroll
        for (int m = 0; m < 4; m++)
            af[m] = *(const bf16x8*)&As[(wr + m * 16 + fr) * 32 + kg * 8];
#pragma unroll
        for (int n = 0; n < 4; n++)
            bq[n] = *(const bf16x8*)&Bs[(wc + n * 16 + fr) * 32 + kg * 8];
#pragma unroll
        for (int m = 0; m < 4; m++)
#pragma unroll
            for (int n = 0; n < 4; n++)
                acc[m][n] = __builtin_amdgcn_mfma_f32_16x16x32_bf16(
                    af[m], bq[n], acc[m][n], 0, 0, 0);
    }
    int g4 = (lane >> 4) * 4;
#pragma unroll
    for (int m = 0; m < 4; m++) {
#pragma unroll
        for (int g = 0; g < 4; g++) {
            long r = (long)blockIdx.x * 128 + wr + m * 16 + g4 + g;
#pragma unroll
            for (int n = 0; n < 4; n++) {
                int col = blockIdx.y * 128 + wc + n * 16 + fr;
                float v = acc[m][n][g];
                if (MODE == 0) {
                    v += (col < 512) ? bias0[col] : bias1[col - 512];
                    v = fmaxf(v, 0.f);
                    C0[r * 1024 + col] = (bf16_t)v;
                } else {
                    v += z ? bias1[col] : bias0[col];
                    (z ? C1 : C0)[r * (long)KP + col] = (bf16_t)v;
                }
            }
        }
    }
}

// ---------- 256x256x64 8-phase counted-vmcnt GEMM, supertile+XCD swizzle ----------
// Exact round-2 pipeline (even NTT=18, no tail).
// MODE 2: C=T bf16: A=e1[8192][KP], B=Wbt[3072][KP]; grid 384 (32 bx x 12 byN)
// MODE 3: C=out f32: A=s1 per-batch, B=T per-batch; grid 192 (2 bx x 6 yy x 16 zz)
template <int MODE>
__global__ __launch_bounds__(512) void gemm8(
    const bf16_t* __restrict__ A, const bf16_t* __restrict__ B,
    void* __restrict__ C) {
    __shared__ char smem[131072];   // A: [0,64K) 2 bufs; B: [64K,128K) 2 bufs
    int tid = threadIdx.x;
    int wg = blockIdx.x;
    int bx, zz, yy;
    if (MODE == 2) {
        int wgid = (wg & 7) * 48 + (wg >> 3);       // XCD-contiguous
        int wi = wgid & 15, st = wgid >> 4;         // supertile 4x4
        bx = (st & 7) * 4 + (wi & 3);               // 0..31
        int byN = (st >> 3) * 4 + (wi >> 2);        // 0..11
        zz = byN >> 2; yy = byN & 3;
    } else {
        int wgid = (wg & 7) * 24 + (wg >> 3);       // supertile 2x12 per XCD
        bx = wgid & 1;
        int byz = wgid >> 1;                        // 0..95
        zz = byz / 6; yy = byz % 6;
    }
    long Aoff = (MODE == 2) ? (long)bx * 256 * KP
                            : ((long)zz * 512 + bx * 256) * KP;
    long Boff = (MODE == 2) ? (long)(zz * 4 + yy) * 256 * KP
                            : ((long)zz * 1536 + yy * 256) * KP;
    const bf16_t* At = A + Aoff;
    const bf16_t* Bt = B + Boff;
    int lane = tid & 63, wv = tid >> 6, wm = wv >> 2, wn = wv & 3;
    int fr = lane & 15, kg = lane >> 4;
    int row0 = tid >> 3, sc0 = (tid & 7) ^ (row0 & 7);
    int q1 = tid + 512;
    int row1 = q1 >> 3, sc1 = (q1 & 7) ^ (row1 & 7);

    auto STAGE = [&](int mat, int ht, int tile) {
        int ts = tile <= NTT - 1 ? tile : NTT - 1;   // clamp source
        int buf = tile & 1;
        const bf16_t* base = mat ? Bt : At;
        long rb = (long)ht * 128;
        const bf16_t* g0 = base + (rb + row0) * KP + ts * 64 + sc0 * 8;
        const bf16_t* g1 = base + (rb + row1) * KP + ts * 64 + sc1 * 8;
        char* l = smem + (mat ? 65536 : 0) + buf * 32768 + ht * 16384;
        gload_lds16(g0, l + tid * 16);
        gload_lds16(g1, l + 8192 + tid * 16);
    };
    auto RDA = [&](int buf, int h, int m, int kk) -> bf16x8 {
        int row = wm * 128 + h * 64 + m * 16 + fr;
        int c16 = kk * 4 + kg;
        int off = buf * 32768 + row * 128 + ((c16 ^ (row & 7)) << 4);
        return *(const bf16x8*)(smem + off);
    };
    auto RDB = [&](int buf, int v, int n, int kk) -> bf16x8 {
        int row = wn * 64 + v * 32 + n * 16 + fr;
        int c16 = kk * 4 + kg;
        int off = 65536 + buf * 32768 + row * 128 + ((c16 ^ (row & 7)) << 4);
        return *(const bf16x8*)(smem + off);
    };

    f32x4 acc[8][4] = {};

    // prologue: tile0 fully + tile1 A-halves; leave 4 loads in flight
    STAGE(0, 0, 0); STAGE(0, 1, 0); STAGE(1, 0, 0); STAGE(1, 1, 0);
    STAGE(0, 0, 1); STAGE(0, 1, 1);
    asm volatile("s_waitcnt vmcnt(4)" ::: "memory");
    __builtin_amdgcn_s_barrier();

    auto doTile = [&](int buf, int sB, int sA) {
        bf16x8 aL[4][2], aH[4][2], bE[2][2], bO[2][2];
        // phase a
#pragma unroll
        for (int m = 0; m < 4; m++)
#pragma unroll
            for (int k = 0; k < 2; k++) aL[m][k] = RDA(buf, 0, m, k);
#pragma unroll
        for (int n = 0; n < 2; n++)
#pragma unroll
            for (int k = 0; k < 2; k++) bE[n][k] = RDB(buf, 0, n, k);
        STAGE(1, 0, sB);
        __builtin_amdgcn_s_barrier();
        __builtin_amdgcn_s_setprio(1);
#pragma unroll
        for (int m = 0; m < 4; m++)
#pragma unroll
            for (int n = 0; n < 2; n++)
#pragma unroll
                for (int k = 0; k < 2; k++)
                    acc[m][n] = __builtin_amdgcn_mfma_f32_16x16x32_bf16(
                        aL[m][k], bE[n][k], acc[m][n], 0, 0, 0);
        __builtin_amdgcn_s_setprio(0);
        __builtin_amdgcn_s_barrier();
        // phase b
#pragma unroll
        for (int n = 0; n < 2; n++)
#pragma unroll
            for (int k = 0; k < 2; k++) bO[n][k] = RDB(buf, 1, n, k);
        STAGE(1, 1, sB);
        __builtin_amdgcn_s_barrier();
        __builtin_amdgcn_s_setprio(1);
#pragma unroll
        for (int m = 0; m < 4; m++)
#pragma unroll
            for (int n = 0; n < 2; n++)
#pragma unroll
                for (int k = 0; k < 2; k++)
                    acc[m][2 + n] = __builtin_amdgcn_mfma_f32_16x16x32_bf16(
                        aL[m][k], bO[n][k], acc[m][2 + n], 0, 0, 0);
        __builtin_amdgcn_s_setprio(0);
        __builtin_amdgcn_s_barrier();
        // phase c
#pragma unroll
        for (int m = 0; m < 4; m++)
#pragma unroll
            for (int k = 0; k < 2; k++) aH[m][k] = RDA(buf, 1, m, k);
        STAGE(0, 0, sA);
        __builtin_amdgcn_s_barrier();
        __builtin_amdgcn_s_setprio(1);
#pragma unroll
        for (int m = 0; m < 4; m++)
#pragma unroll
            for (int n = 0; n < 2; n++)
#pragma unroll
                for (int k = 0; k < 2; k++)
                    acc[4 + m][n] = __builtin_amdgcn_mfma_f32_16x16x32_bf16(
                        aH[m][k], bE[n][k], acc[4 + m][n], 0, 0, 0);
        __builtin_amdgcn_s_setprio(0);
        __builtin_amdgcn_s_barrier();
        // phase d
        STAGE(0, 1, sA);
        __builtin_amdgcn_s_barrier();
        __builtin_amdgcn_s_setprio(1);
#pragma unroll
        for (int m = 0; m < 4; m++)
#pragma unroll
            for (int n = 0; n < 2; n++)
#pragma unroll
                for (int k = 0; k < 2; k++)
                    acc[4 + m][2 + n] = __builtin_amdgcn_mfma_f32_16x16x32_bf16(
                        aH[m][k], bO[n][k], acc[4 + m][2 + n], 0, 0, 0);
        __builtin_amdgcn_s_setprio(0);
        asm volatile("s_waitcnt vmcnt(4)" ::: "memory");
        __builtin_amdgcn_s_barrier();
    };

    for (int it = 0; it < NTT / 2; ++it) {
        int t = 2 * it;
        doTile(0, t + 1, t + 2);
        doTile(1, t + 2, t + 3);
    }

    // epilogue
#pragma unroll
    for (int mf = 0; mf < 8; mf++) {
#pragma unroll
        for (int g = 0; g < 4; g++) {
            int rloc = wm * 128 + mf * 16 + kg * 4 + g;
#pragma unroll
            for (int nf = 0; nf < 4; nf++) {
                int col = wn * 64 + nf * 16 + fr;
                float v = acc[mf][nf][g];
                if (MODE == 2) {
                    long r = (long)bx * 256 + rloc;
                    ((bf16_t*)C)[(r * 3 + zz) * (long)KP + yy * 256 + col] = (bf16_t)v;
                } else {
                    long r = (long)bx * 256 + rloc;
                    ((float*)C)[(long)zz * (512L * YC) + r * YC + yy * 256 + col] = v;
                }
            }
        }
    }
}

extern "C" void kernel_launch(void* const* d_in, const int* in_sizes, int n_in,
                              void* d_out, int out_size, void* d_ws, size_t ws_size,
                              hipStream_t stream) {
    const float* ctx  = (const float*)d_in[0];
    const float* ques = (const float*)d_in[1];
    const float* wsim = (const float*)d_in[2];
    const float* W1s  = (const float*)d_in[3];
    const float* b1s  = (const float*)d_in[4];
    const float* W2s  = (const float*)d_in[5];
    const float* b2s  = (const float*)d_in[6];
    const float* W1e  = (const float*)d_in[7];
    const float* b1e  = (const float*)d_in[8];
    const float* W2e  = (const float*)d_in[9];
    const float* b2e  = (const float*)d_in[10];
    const float* Wb   = (const float*)d_in[11];

    char* ws = (char*)d_ws;
    float*  qw2  = (float*)(ws + OFF_QW2);
    float*  mrow = (float*)(ws + OFF_MROW);
    float*  q2c  = (float*)(ws + OFF_Q2C);
    float*  c2q  = (float*)(ws + OFF_C2Q);
    bf16_t* xb   = (bf16_t*)(ws + OFF_XB);
    bf16_t* hbuf = (bf16_t*)(ws + OFF_HBUF);
    bf16_t* W1c  = (bf16_t*)(ws + OFF_W1C);
    bf16_t* W2c  = (bf16_t*)(ws + OFF_W2C);
    bf16_t* T    = (bf16_t*)(ws + OFF_T);
    bf16_t* s1   = (bf16_t*)(ws + OFF_S1);
    bf16_t* e1   = (bf16_t*)(ws + OFF_E1);
    bf16_t* Wbt  = (bf16_t*)(ws + OFF_WBT);

    // weight prep + attention front-end
    k_qw2<<<256, 256, 0, stream>>>(ques, wsim, qw2);
    k_wtrans<<<dim3(32, 16), 256, 0, stream>>>(W1s, W1c, 1024, 512);
    k_wtrans<<<dim3(32, 16), 256, 0, stream>>>(W1e, W1c + 512 * 1024, 1024, 512);
    k_wtrans<<<dim3(16, 32), 256, 0, stream>>>(W2s, W2c, 512, 1024);
    k_wtrans<<<dim3(16, 32), 256, 0, stream>>>(W2e, W2c + 1024 * 512, 512, 1024);
    k_wb<<<3072, 256, 0, stream>>>(Wb, Wbt);
    k_attn<<<Bsz * 32, 256, 0, stream>>>(ctx, ques, wsim, qw2, c2q, mrow);
    k_q2c<<<128, 256, 0, stream>>>(ctx, mrow, q2c);
    k_buildx<<<NROW, 256, 0, stream>>>(ctx, c2q, q2c, xb);
    k_initse<<<4096, 256, 0, stream>>>(s1, e1);

    // FFW: hbuf = relu(x@[W1s|W1e] + [b1s|b1e]); {s1,e1} = h_z@W2z + b2z
    gemm_nt<0><<<dim3(64, 8), 256, 0, stream>>>(xb, W1c, b1s, b1e, hbuf, nullptr);
    gemm_nt<1><<<dim3(64, 8, 2), 256, 0, stream>>>(hbuf, W2c, b2s, b2e, s1, e1);
    // g-column of T (i = 1024) + zero T pad cols
    k_gcol<<<2048, 256, 0, stream>>>(e1, Wb, T);
    // T core: [8192x3072] = e1 @ Wbt^T (per-class folded into N)
    gemm8<2><<<384, 512, 0, stream>>>(e1, Wbt, T);
    // out = s1 @ T^T per batch
    gemm8<3><<<192, 512, 0, stream>>>(s1, T, d_out);
}

// Round 6
// 298.387 us; speedup vs baseline: 1.2044x; 1.0548x over previous
//
#include <hip/hip_runtime.h>
#include <hip/hip_bf16.h>
#include <math.h>

typedef __bf16 bf16_t;
typedef bf16_t bf16x4 __attribute__((ext_vector_type(4)));
typedef bf16_t bf16x8 __attribute__((ext_vector_type(8)));
typedef float f32x4 __attribute__((ext_vector_type(4)));

#define Bsz 16
#define LCc 512
#define LQq 64
#define Hd 256
#define Dd 1024
#define DFFd 512
#define DP1 1025
#define KP 1152      // padded contraction dim, 18 tiles of 64 (EVEN -> no tail)
#define NROW 8192
#define YC 1536

// ---- workspace layout (bytes). T aliases the early-dead region. ----
#define OFF_T    0L          // 24576*1152*2 = 56623104
#define OFF_QW2  0L
#define OFF_MROW 4096L
#define OFF_Q2C  36864L
#define OFF_C2Q  53248L      // 8388608
#define OFF_XB   8441856L    // 16777216
#define OFF_HBUF 25219072L   // 16777216
#define OFF_W1C  41996288L   // 2097152
#define OFF_W2C  44093440L   // 2097152 (ends 46190592 < 56623104)
#define OFF_S1   56623104L   // 18874368
#define OFF_E1   75497472L   // 18874368
#define OFF_WBT  94371840L   // 3072*1152*2 = 7077888 ; end = 101449728

static __device__ __forceinline__ void gload_lds16(const void* g, void* l) {
    __builtin_amdgcn_global_load_lds(
        (const __attribute__((address_space(1))) void*)g,
        (__attribute__((address_space(3))) void*)l, 16, 0, 0);
}

// ---------- qw2[b,j] = dot(ques[b,j,:], w2) ----------
__global__ __launch_bounds__(256) void k_qw2(const float* __restrict__ ques,
                                             const float* __restrict__ wsim,
                                             float* __restrict__ qw2) {
    int row = blockIdx.x * 4 + (threadIdx.x >> 6);
    int lane = threadIdx.x & 63;
    float4 q = *(const float4*)&ques[(long)row * Hd + lane * 4];
    float4 w = *(const float4*)&wsim[Hd + lane * 4];
    float p = q.x * w.x + q.y * w.y + q.z * w.z + q.w * w.w;
#pragma unroll
    for (int o = 32; o >= 1; o >>= 1) p += __shfl_xor(p, o, 64);
    if (lane == 0) qw2[row] = p;
}

// ---------- weight transpose f32 [K][N] -> bf16 [N][K], z-pair merged ----------
__global__ __launch_bounds__(256) void k_wtrans2(const float* __restrict__ in0,
                                                 const float* __restrict__ in1,
                                                 bf16_t* __restrict__ out,
                                                 int K, int N) {
    __shared__ float tile[32][33];
    const float* in = blockIdx.z ? in1 : in0;
    bf16_t* o = out + (long)blockIdx.z * K * N;
    int k0 = blockIdx.x * 32, n0 = blockIdx.y * 32;
    int r = threadIdx.x >> 5, c = threadIdx.x & 31;
#pragma unroll
    for (int rr = 0; rr < 32; rr += 8)
        tile[r + rr][c] = in[(long)(k0 + r + rr) * N + n0 + c];
    __syncthreads();
#pragma unroll
    for (int rr = 0; rr < 32; rr += 8)
        o[(long)(n0 + r + rr) * K + k0 + c] = (bf16_t)tile[c][r + rr];
}

// ---------- Wbt[c*1024+i][j] = Wb[i,c,j], bf16, [3072][1152], cols>=1025 zero ----------
__global__ __launch_bounds__(256) void k_wb(const float* __restrict__ Wb,
                                            bf16_t* __restrict__ Wbt) {
    int rw = blockIdx.x;            // c*1024 + i
    int c = rw >> 10, i = rw & 1023;
    int tid = threadIdx.x;
    const float* src = Wb + ((long)i * 3 + c) * DP1;
    bf16_t* orow = Wbt + (long)rw * KP;
#pragma unroll
    for (int p = 0; p < 2; p++) {
        int j4 = tid + p * 256;
        if (j4 < KP / 4) {
            int j = j4 * 4;
            float x = (j + 0 < DP1) ? src[j + 0] : 0.f;
            float y = (j + 1 < DP1) ? src[j + 1] : 0.f;
            float z = (j + 2 < DP1) ? src[j + 2] : 0.f;
            float w = (j + 3 < DP1) ? src[j + 3] : 0.f;
            bf16x4 bv = {(bf16_t)x, (bf16_t)y, (bf16_t)z, (bf16_t)w};
            *(bf16x4*)&orow[j] = bv;
        }
    }
}

// ---------- init cols [1024..1151] of s1,e1: col1024=1, rest 0 ----------
__global__ __launch_bounds__(256) void k_initse(bf16_t* __restrict__ s1,
                                                bf16_t* __restrict__ e1) {
    int idx = blockIdx.x * 256 + threadIdx.x;   // 8192*128
    long r = idx >> 7; int cc = idx & 127;
    bf16_t v = (bf16_t)(cc == 0 ? 1.0f : 0.0f);
    s1[r * KP + 1024 + cc] = v;
    e1[r * KP + 1024 + cc] = v;
}

// ---------- attention: sim -> softmax_j -> c2q, rowmax -> mrow ----------
__global__ __launch_bounds__(256) void k_attn(const float* __restrict__ ctx,
                                              const float* __restrict__ ques,
                                              const float* __restrict__ wsim,
                                              const float* __restrict__ qw2,
                                              float* __restrict__ c2q,
                                              float* __restrict__ mrow) {
    __shared__ bf16x4 qlds[LQq * 64];
    __shared__ float cw3s[4][Hd];
    __shared__ float awave[4][LQq];
    int b = blockIdx.x >> 5;
    int itile = blockIdx.x & 31;
    int tid = threadIdx.x, wid = tid >> 6, lane = tid & 63;
#pragma unroll
    for (int p = 0; p < 16; p++) {
        int s = tid + p * 256;
        int j = s >> 6, h4s = s & 63;
        int h4 = h4s ^ (j & 15);
        float4 v = *(const float4*)&ques[((long)b * LQq + j) * Hd + h4 * 4];
        bf16x4 bv = {(bf16_t)v.x, (bf16_t)v.y, (bf16_t)v.z, (bf16_t)v.w};
        qlds[s] = bv;
    }
    float qw2r = qw2[b * LQq + lane];
    float4 w1v = *(const float4*)&wsim[lane * 4];
    float4 w3v = *(const float4*)&wsim[2 * Hd + lane * 4];
    __syncthreads();
    for (int rr = 0; rr < 4; rr++) {
        int i = itile * 16 + wid * 4 + rr;
        float4 cv = *(const float4*)&ctx[((long)b * LCc + i) * Hd + lane * 4];
        float cw1p = cv.x * w1v.x + cv.y * w1v.y + cv.z * w1v.z + cv.w * w1v.w;
        float4 c3;
        c3.x = cv.x * w3v.x; c3.y = cv.y * w3v.y;
        c3.z = cv.z * w3v.z; c3.w = cv.w * w3v.w;
        *(float4*)&cw3s[wid][lane * 4] = c3;
#pragma unroll
        for (int o = 32; o >= 1; o >>= 1) cw1p += __shfl_xor(cw1p, o, 64);
        __syncthreads();
        float s = cw1p + qw2r;
#pragma unroll 8
        for (int h4 = 0; h4 < 64; h4++) {
            float4 c3v = *(const float4*)&cw3s[wid][h4 * 4];
            bf16x4 qb = qlds[lane * 64 + (h4 ^ (lane & 15))];
            s += c3v.x * (float)qb[0] + c3v.y * (float)qb[1]
               + c3v.z * (float)qb[2] + c3v.w * (float)qb[3];
        }
        float mx = s;
#pragma unroll
        for (int o = 32; o >= 1; o >>= 1) mx = fmaxf(mx, __shfl_xor(mx, o, 64));
        if (lane == 0) mrow[b * LCc + i] = mx;
        float pe = __expf(s - mx);
        float den = pe;
#pragma unroll
        for (int o = 32; o >= 1; o >>= 1) den += __shfl_xor(den, o, 64);
        awave[wid][lane] = pe / den;
        __syncthreads();
        float4 accv = {0.f, 0.f, 0.f, 0.f};
#pragma unroll 8
        for (int j = 0; j < 64; j++) {
            float aj = awave[wid][j];
            bf16x4 qb = qlds[j * 64 + (lane ^ (j & 15))];
            accv.x = fmaf(aj, (float)qb[0], accv.x);
            accv.y = fmaf(aj, (float)qb[1], accv.y);
            accv.z = fmaf(aj, (float)qb[2], accv.z);
            accv.w = fmaf(aj, (float)qb[3], accv.w);
        }
        *(float4*)&c2q[((long)b * LCc + i) * Hd + lane * 4] = accv;
        __syncthreads();
    }
}

// ---------- q2c: 128 blocks = 16 b x 8 h-chunks ----------
__global__ __launch_bounds__(256) void k_q2c(const float* __restrict__ ctx,
                                             const float* __restrict__ mrow,
                                             float* __restrict__ q2c) {
    __shared__ float wbuf[LCc];
    __shared__ float red[8];
    __shared__ float part[8][32];
    int blk = blockIdx.x;
    int b = blk >> 3, hc = blk & 7;
    int tid = threadIdx.x;
    float v0 = mrow[b * LCc + tid], v1 = mrow[b * LCc + 256 + tid];
    float m = fmaxf(v0, v1);
#pragma unroll
    for (int o = 32; o >= 1; o >>= 1) m = fmaxf(m, __shfl_xor(m, o, 64));
    if ((tid & 63) == 0) red[tid >> 6] = m;
    __syncthreads();
    float M = fmaxf(fmaxf(red[0], red[1]), fmaxf(red[2], red[3]));
    float e0 = __expf(v0 - M), e1v = __expf(v1 - M);
    float sm = e0 + e1v;
#pragma unroll
    for (int o = 32; o >= 1; o >>= 1) sm += __shfl_xor(sm, o, 64);
    if ((tid & 63) == 0) red[4 + (tid >> 6)] = sm;
    __syncthreads();
    float S = red[4] + red[5] + red[6] + red[7];
    wbuf[tid] = e0 / S;
    wbuf[tid + 256] = e1v / S;
    __syncthreads();
    int ig = tid >> 5, h31 = tid & 31;
    int h = hc * 32 + h31;
    float acc = 0.f;
#pragma unroll 4
    for (int ii = 0; ii < 64; ii++) {
        int i = ig * 64 + ii;
        acc = fmaf(wbuf[i], ctx[((long)b * LCc + i) * Hd + h], acc);
    }
    part[ig][h31] = acc;
    __syncthreads();
    if (tid < 32) {
        float s = 0.f;
#pragma unroll
        for (int k = 0; k < 8; k++) s += part[k][tid];
        q2c[b * Hd + hc * 32 + tid] = s;
    }
}

// ---------- x = [ctx, c2q, ctx*c2q, ctx*q2c] -> bf16 [8192][1024] ----------
__global__ __launch_bounds__(256) void k_buildx(const float* __restrict__ ctx,
                                                const float* __restrict__ c2q,
                                                const float* __restrict__ q2c,
                                                bf16_t* __restrict__ xb) {
    long r = blockIdx.x;
    int b = (int)(r >> 9);
    int tid = threadIdx.x;
    int sec = tid >> 6, h4 = tid & 63;
    float4 cv = *(const float4*)&ctx[r * Hd + h4 * 4];
    float4 v;
    if (sec == 0) {
        v = cv;
    } else if (sec == 1) {
        v = *(const float4*)&c2q[r * Hd + h4 * 4];
    } else if (sec == 2) {
        float4 q = *(const float4*)&c2q[r * Hd + h4 * 4];
        v.x = cv.x * q.x; v.y = cv.y * q.y; v.z = cv.z * q.z; v.w = cv.w * q.w;
    } else {
        float4 q = *(const float4*)&q2c[b * Hd + h4 * 4];
        v.x = cv.x * q.x; v.y = cv.y * q.y; v.z = cv.z * q.z; v.w = cv.w * q.w;
    }
    bf16x4 bv = {(bf16_t)v.x, (bf16_t)v.y, (bf16_t)v.z, (bf16_t)v.w};
    *(bf16x4*)&xb[r * Dd + sec * Hd + h4 * 4] = bv;
}

// ---------- g-column + T pad-zero ----------
__global__ __launch_bounds__(256) void k_gcol(const bf16_t* __restrict__ e1,
                                              const float* __restrict__ Wb,
                                              bf16_t* __restrict__ T) {
    int tid = threadIdx.x;
    int wv = tid >> 6, lane = tid & 63;
    long r = (long)blockIdx.x * 4 + wv;
    bf16x8 ea = *(const bf16x8*)&e1[r * KP + lane * 16];
    bf16x8 eb = *(const bf16x8*)&e1[r * KP + lane * 16 + 8];
    const float* wr0 = Wb + (long)3072 * DP1;   // row block i=1024
#pragma unroll
    for (int c = 0; c < 3; c++) {
        const float* wr = wr0 + (long)c * DP1 + lane * 16;
        float acc = 0.f;
#pragma unroll
        for (int k = 0; k < 8; k++) {
            acc = fmaf((float)ea[k], wr[k], acc);
            acc = fmaf((float)eb[k], wr[8 + k], acc);
        }
#pragma unroll
        for (int o = 32; o >= 1; o >>= 1) acc += __shfl_xor(acc, o, 64);
        long rowb = (r * 3 + c) * (long)KP;
        if (lane == 0)
            T[rowb + 1024] = (bf16_t)(acc + wr0[(long)c * DP1 + 1024]);
        for (int jj = 1025 + lane; jj < KP; jj += 64)
            T[rowb + jj] = (bf16_t)0.f;
    }
}

// ---------- unified 8-phase counted-vmcnt GEMM: tile 256 x (64*NFR), BK=64 ----------
// MODE 0 (FFW1): A=xb lda1024, B=W1c ldb1024, NT=16, NFR=2, grid 256 (32bx x 8by)
//                C0=hbuf bf16 ldc1024, bias b0|b1 split at 512, relu
// MODE 1 (FFW2): A=hbuf+z*512 lda1024, B=W2c+z*512K ldb512, NT=8, NFR=4,
//                grid 256 (32bx x 2by x 2z... by 0..3), C=(z?e1:s1) ldc KP, bias
// MODE 2 (Tcore): A=e1, B=Wbt, ld KP, NT=18, NFR=3, grid 512 (32bx x 16byN)
//                C0=T bf16: colg=(cls,i) split
// MODE 3 (out):  A=s1_z, B=T_z, ld KP, NT=18, NFR=3, grid 256 (2bx x 8yy x 16zz)
//                C0=out f32
template <int NT, int NFR, int MODE>
__global__ __launch_bounds__(512) void gemm8p(
    const bf16_t* __restrict__ A, const bf16_t* __restrict__ B,
    const float* __restrict__ b0, const float* __restrict__ b1,
    void* __restrict__ C0, void* __restrict__ C1) {
    constexpr int LDA = (MODE <= 1) ? 1024 : KP;
    constexpr int LDB = (MODE == 0) ? 1024 : (MODE == 1) ? 512 : KP;
    constexpr int BEn = (NFR + 1) / 2;
    constexpr int BOn = NFR / 2;
    __shared__ char smem[65536 + NFR * 16384];   // A 2x16K dbuf | B 2xNFR*8K dbuf
    int tid = threadIdx.x;
    int wg = blockIdx.x;
    int xcd = wg & 7, idx = wg >> 3;
    int bx, by, z = 0;
    if (MODE == 0) {
        bx = (xcd & 3) * 8 + (idx & 7); by = (xcd >> 2) * 4 + (idx >> 3);
    } else if (MODE == 1) {
        z = idx >> 4; bx = (xcd & 3) * 8 + (idx & 7); by = (xcd >> 2) * 2 + ((idx >> 3) & 1);
    } else if (MODE == 2) {
        bx = (xcd & 3) * 8 + (idx & 7); by = (xcd >> 2) * 8 + (idx >> 3);
    } else {
        z = xcd * 2 + (idx >> 4); bx = idx & 1; by = (idx >> 1) & 7;
    }
    const bf16_t* At;
    const bf16_t* Bt;
    if (MODE == 0) {
        At = A + (long)bx * 256 * LDA;            Bt = B + (long)by * 128 * LDB;
    } else if (MODE == 1) {
        At = A + (long)z * 512 + (long)bx * 256 * LDA;
        Bt = B + (long)z * 524288 + (long)by * 256 * LDB;
    } else if (MODE == 2) {
        At = A + (long)bx * 256 * LDA;            Bt = B + (long)by * 192 * LDB;
    } else {
        At = A + ((long)z * 512 + bx * 256) * LDA;
        Bt = B + ((long)z * 1536 + by * 192) * LDB;
    }
    int lane = tid & 63, wv = tid >> 6, wm = wv >> 2, wn = wv & 3;
    int fr = lane & 15, kg = lane >> 4;
    int row0 = tid >> 3, sc0 = (tid & 7) ^ (row0 & 7);
    int q1 = tid + 512;
    int row1 = q1 >> 3, sc1 = (q1 & 7) ^ (row1 & 7);

    auto stageA = [&](int half, int tile) {
        int ts = tile <= NT - 1 ? tile : NT - 1;   // clamp source
        int buf = tile & 1;
        long rb = (long)half * 128;
        const bf16_t* g0 = At + (rb + row0) * LDA + ts * 64 + sc0 * 8;
        const bf16_t* g1 = At + (rb + row1) * LDA + ts * 64 + sc1 * 8;
        char* l = smem + buf * 32768 + half * 16384;
        gload_lds16(g0, l + tid * 16);
        gload_lds16(g1, l + 8192 + tid * 16);
    };
    auto stageB = [&](int j, int tile) {          // one 64-row call
        int ts = tile <= NT - 1 ? tile : NT - 1;
        int buf = tile & 1;
        const bf16_t* g0 = Bt + (long)(j * 64 + row0) * LDB + ts * 64 + sc0 * 8;
        char* l = smem + 65536 + buf * (NFR * 8192) + j * 8192;
        gload_lds16(g0, l + tid * 16);
    };
    auto RDA = [&](int buf, int h, int m, int kk) -> bf16x8 {
        int row = wm * 128 + h * 64 + m * 16 + fr;
        int c16 = kk * 4 + kg;
        int off = buf * 32768 + row * 128 + ((c16 ^ (row & 7)) << 4);
        return *(const bf16x8*)(smem + off);
    };
    auto RDB = [&](int buf, int n, int kk) -> bf16x8 {
        int row = wn * (16 * NFR) + n * 16 + fr;
        int c16 = kk * 4 + kg;
        int off = 65536 + buf * (NFR * 8192) + row * 128 + ((c16 ^ (row & 7)) << 4);
        return *(const bf16x8*)(smem + off);
    };

    f32x4 acc[8][NFR] = {};

    // prologue: T0 A(4 calls) + T0 B(NFR) + T1 A(4); leave last 4 (T1-A) in flight
    stageA(0, 0); stageA(1, 0);
#pragma unroll
    for (int j = 0; j < NFR; j++) stageB(j, 0);
    stageA(0, 1); stageA(1, 1);
    asm volatile("s_waitcnt vmcnt(4)" ::: "memory");
    __builtin_amdgcn_s_barrier();

    auto doTile = [&](int buf, int sB, int sA) {
        bf16x8 aL[4][2], aH[4][2], bE[BEn][2], bO[BOn][2];
        // phase a: read A-h0 + B-even, stage B[0..BEn), MFMA (h0, even)
#pragma unroll
        for (int m = 0; m < 4; m++)
#pragma unroll
            for (int k = 0; k < 2; k++) aL[m][k] = RDA(buf, 0, m, k);
#pragma unroll
        for (int n = 0; n < BEn; n++)
#pragma unroll
            for (int k = 0; k < 2; k++) bE[n][k] = RDB(buf, n, k);
#pragma unroll
        for (int j = 0; j < BEn; j++) stageB(j, sB);
        __builtin_amdgcn_s_barrier();
        __builtin_amdgcn_s_setprio(1);
#pragma unroll
        for (int m = 0; m < 4; m++)
#pragma unroll
            for (int n = 0; n < BEn; n++)
#pragma unroll
                for (int k = 0; k < 2; k++)
                    acc[m][n] = __builtin_amdgcn_mfma_f32_16x16x32_bf16(
                        aL[m][k], bE[n][k], acc[m][n], 0, 0, 0);
        __builtin_amdgcn_s_setprio(0);
        __builtin_amdgcn_s_barrier();
        // phase b: read B-odd, stage B[BEn..NFR), MFMA (h0, odd)
#pragma unroll
        for (int n = 0; n < BOn; n++)
#pragma unroll
            for (int k = 0; k < 2; k++) bO[n][k] = RDB(buf, BEn + n, k);
#pragma unroll
        for (int j = BEn; j < NFR; j++) stageB(j, sB);
        __builtin_amdgcn_s_barrier();
        __builtin_amdgcn_s_setprio(1);
#pragma unroll
        for (int m = 0; m < 4; m++)
#pragma unroll
            for (int n = 0; n < BOn; n++)
#pragma unroll
                for (int k = 0; k < 2; k++)
                    acc[m][BEn + n] = __builtin_amdgcn_mfma_f32_16x16x32_bf16(
                        aL[m][k], bO[n][k], acc[m][BEn + n], 0, 0, 0);
        __builtin_amdgcn_s_setprio(0);
        __builtin_amdgcn_s_barrier();
        // phase c: read A-h1, stage A0(sA), MFMA (h1, even)
#pragma unroll
        for (int m = 0; m < 4; m++)
#pragma unroll
            for (int k = 0; k < 2; k++) aH[m][k] = RDA(buf, 1, m, k);
        stageA(0, sA);
        __builtin_amdgcn_s_barrier();
        __builtin_amdgcn_s_setprio(1);
#pragma unroll
        for (int m = 0; m < 4; m++)
#pragma unroll
            for (int n = 0; n < BEn; n++)
#pragma unroll
                for (int k = 0; k < 2; k++)
                    acc[4 + m][n] = __builtin_amdgcn_mfma_f32_16x16x32_bf16(
                        aH[m][k], bE[n][k], acc[4 + m][n], 0, 0, 0);
        __builtin_amdgcn_s_setprio(0);
        __builtin_amdgcn_s_barrier();
        // phase d: stage A1(sA), MFMA (h1, odd), counted vmcnt, barrier
        stageA(1, sA);
        __builtin_amdgcn_s_barrier();
        __builtin_amdgcn_s_setprio(1);
#pragma unroll
        for (int m = 0; m < 4; m++)
#pragma unroll
            for (int n = 0; n < BOn; n++)
#pragma unroll
                for (int k = 0; k < 2; k++)
                    acc[4 + m][BEn + n] = __builtin_amdgcn_mfma_f32_16x16x32_bf16(
                        aH[m][k], bO[n][k], acc[4 + m][BEn + n], 0, 0, 0);
        __builtin_amdgcn_s_setprio(0);
        asm volatile("s_waitcnt vmcnt(4)" ::: "memory");
        __builtin_amdgcn_s_barrier();
    };

    for (int it = 0; it < NT / 2; ++it) {
        int t = 2 * it;
        doTile(0, t + 1, t + 2);
        doTile(1, t + 2, t + 3);
    }

    // epilogue
#pragma unroll
    for (int mf = 0; mf < 8; mf++) {
#pragma unroll
        for (int g = 0; g < 4; g++) {
            int rloc = wm * 128 + mf * 16 + kg * 4 + g;
            long r = (long)bx * 256 + rloc;
#pragma unroll
            for (int nf = 0; nf < NFR; nf++) {
                int col = wn * (16 * NFR) + nf * 16 + fr;
                float v = acc[mf][nf][g];
                if (MODE == 0) {
                    int colg = by * 128 + col;
                    v += (colg < 512) ? b0[colg] : b1[colg - 512];
                    v = fmaxf(v, 0.f);
                    ((bf16_t*)C0)[r * 1024 + colg] = (bf16_t)v;
                } else if (MODE == 1) {
                    int colg = by * 256 + col;
                    v += z ? b1[colg] : b0[colg];
                    ((bf16_t*)(z ? C1 : C0))[r * (long)KP + colg] = (bf16_t)v;
                } else if (MODE == 2) {
                    int colg = by * 192 + col;
                    int cls = colg >> 10, i = colg & 1023;
                    ((bf16_t*)C0)[(r * 3 + cls) * (long)KP + i] = (bf16_t)v;
                } else {
                    int colg = by * 192 + col;
                    ((float*)C0)[(long)z * (512L * YC) + r * YC + colg] = v;
                }
            }
        }
    }
}

extern "C" void kernel_launch(void* const* d_in, const int* in_sizes, int n_in,
                              void* d_out, int out_size, void* d_ws, size_t ws_size,
                              hipStream_t stream) {
    const float* ctx  = (const float*)d_in[0];
    const float* ques = (const float*)d_in[1];
    const float* wsim = (const float*)d_in[2];
    const float* W1s  = (const float*)d_in[3];
    const float* b1s  = (const float*)d_in[4];
    const float* W2s  = (const float*)d_in[5];
    const float* b2s  = (const float*)d_in[6];
    const float* W1e  = (const float*)d_in[7];
    const float* b1e  = (const float*)d_in[8];
    const float* W2e  = (const float*)d_in[9];
    const float* b2e  = (const float*)d_in[10];
    const float* Wb   = (const float*)d_in[11];

    char* ws = (char*)d_ws;
    float*  qw2  = (float*)(ws + OFF_QW2);
    float*  mrow = (float*)(ws + OFF_MROW);
    float*  q2c  = (float*)(ws + OFF_Q2C);
    float*  c2q  = (float*)(ws + OFF_C2Q);
    bf16_t* xb   = (bf16_t*)(ws + OFF_XB);
    bf16_t* hbuf = (bf16_t*)(ws + OFF_HBUF);
    bf16_t* W1c  = (bf16_t*)(ws + OFF_W1C);
    bf16_t* W2c  = (bf16_t*)(ws + OFF_W2C);
    bf16_t* T    = (bf16_t*)(ws + OFF_T);
    bf16_t* s1   = (bf16_t*)(ws + OFF_S1);
    bf16_t* e1   = (bf16_t*)(ws + OFF_E1);
    bf16_t* Wbt  = (bf16_t*)(ws + OFF_WBT);

    // weight prep + attention front-end
    k_qw2<<<256, 256, 0, stream>>>(ques, wsim, qw2);
    k_wtrans2<<<dim3(32, 16, 2), 256, 0, stream>>>(W1s, W1e, W1c, 1024, 512);
    k_wtrans2<<<dim3(16, 32, 2), 256, 0, stream>>>(W2s, W2e, W2c, 512, 1024);
    k_wb<<<3072, 256, 0, stream>>>(Wb, Wbt);
    k_attn<<<Bsz * 32, 256, 0, stream>>>(ctx, ques, wsim, qw2, c2q, mrow);
    k_q2c<<<128, 256, 0, stream>>>(ctx, mrow, q2c);
    k_buildx<<<NROW, 256, 0, stream>>>(ctx, c2q, q2c, xb);
    k_initse<<<4096, 256, 0, stream>>>(s1, e1);

    // FFW1: hbuf = relu(x@[W1s|W1e] + [b1s|b1e])  (256x128 tiles, grid 256)
    gemm8p<16, 2, 0><<<256, 512, 0, stream>>>(xb, W1c, b1s, b1e, hbuf, nullptr);
    // FFW2: {s1,e1} = h_z @ W2z + b2z             (256x256 tiles, grid 256)
    gemm8p<8, 4, 1><<<256, 512, 0, stream>>>(hbuf, W2c, b2s, b2e, s1, e1);
    // g-column of T (i = 1024) + zero T pad cols
    k_gcol<<<2048, 256, 0, stream>>>(e1, Wb, T);
    // T core: [8192x3072] = e1 @ Wbt^T            (256x192 tiles, grid 512 = 2 rounds)
    gemm8p<18, 3, 2><<<512, 512, 0, stream>>>(e1, Wbt, nullptr, nullptr, T, nullptr);
    // out = s1 @ T^T per batch                    (256x192 tiles, grid 256)
    gemm8p<18, 3, 3><<<256, 512, 0, stream>>>(s1, T, nullptr, nullptr, d_out, nullptr);
}